// Round 1
// baseline (1420.500 us; speedup 1.0000x reference)
//
#include <hip/hip_runtime.h>
#include <hip/hip_bf16.h>
#include <math.h>

#define NN 100000
#define EE 800000
#define DD 128
#define OUTC 40

// ---------------- CSR build ----------------
__global__ void k_hist(const int* __restrict__ dst, int* __restrict__ deg, int e) {
  int i = blockIdx.x * 256 + threadIdx.x;
  if (i < e) atomicAdd(&deg[dst[i]], 1);
}

__global__ __launch_bounds__(1024) void k_scan1(const int* __restrict__ deg, int* __restrict__ rp,
                                                int* __restrict__ bsum, int n) {
  __shared__ int s[1024];
  int t = threadIdx.x;
  int i = blockIdx.x * 1024 + t;
  s[t] = (i < n) ? deg[i] : 0;
  __syncthreads();
  for (int off = 1; off < 1024; off <<= 1) {
    int x = (t >= off) ? s[t - off] : 0;
    __syncthreads();
    s[t] += x;
    __syncthreads();
  }
  if (i < n) rp[i + 1] = s[t];
  if (t == 1023) bsum[blockIdx.x] = s[1023];
}

__global__ __launch_bounds__(128) void k_scan2(int* __restrict__ bsum, int nb) {
  __shared__ int s[128];
  int t = threadIdx.x;
  s[t] = (t < nb) ? bsum[t] : 0;
  __syncthreads();
  for (int off = 1; off < 128; off <<= 1) {
    int x = (t >= off) ? s[t - off] : 0;
    __syncthreads();
    s[t] += x;
    __syncthreads();
  }
  if (t < nb) bsum[t] = s[t];
}

__global__ void k_scan3(int* __restrict__ rp, const int* __restrict__ bsum,
                        int* __restrict__ cursor, int n) {
  int i = blockIdx.x * 256 + threadIdx.x;
  if (i == 0) { rp[0] = 0; cursor[0] = 0; }
  if (i < n) {
    int blk = i >> 10;
    int v = rp[i + 1] + ((blk > 0) ? bsum[blk - 1] : 0);
    rp[i + 1] = v;
    cursor[i + 1] = v;
  }
}

__global__ void k_scatter(const int* __restrict__ src, const int* __restrict__ dst,
                          int* __restrict__ cursor, int* __restrict__ col, int e) {
  int i = blockIdx.x * 256 + threadIdx.x;
  if (i < e) {
    int d = dst[i];
    int pos = atomicAdd(&cursor[d], 1);
    col[pos] = src[i];
  }
}

// ---------------- GEMM: out[n][o] = sum_k x[n][k]*W[o][k] + b[o], D=128 ----------------
__global__ __launch_bounds__(256) void k_gemm128(const float* __restrict__ x, const float* __restrict__ W,
                                                 const float* __restrict__ bias, float* __restrict__ out, int n) {
  __shared__ float xT[32][129];
  int t = threadIdx.x;
  int wave = t >> 6, lane = t & 63;
  int o0 = __builtin_amdgcn_readfirstlane((wave & 1) * 64);   // wave-uniform output half
  int nl = ((wave >> 1) << 6) + lane;                          // node_local in [0,128)
  int node0 = blockIdx.x * 128;
  float acc[64];
#pragma unroll
  for (int j = 0; j < 64; ++j) acc[j] = bias[o0 + j];
  for (int k0 = 0; k0 < DD; k0 += 32) {
    __syncthreads();
#pragma unroll
    for (int i = 0; i < 16; ++i) {
      int flat = i * 256 + t;
      int kl = flat & 31, nn = flat >> 5;
      int node = node0 + nn;
      xT[kl][nn] = (node < n) ? x[node * DD + k0 + kl] : 0.f;
    }
    __syncthreads();
    float xv[32];
#pragma unroll
    for (int kk = 0; kk < 32; ++kk) xv[kk] = xT[kk][nl];
#pragma unroll
    for (int j = 0; j < 64; ++j) {
      const float* wr = W + (o0 + j) * DD + k0;   // uniform base -> scalar loads
#pragma unroll
      for (int kk = 0; kk < 32; ++kk)
        acc[j] = fmaf(xv[kk], wr[kk], acc[j]);
    }
  }
  int node = node0 + nl;
  if (node < n) {
    float* op = out + node * DD + o0;
#pragma unroll
    for (int j = 0; j < 64; ++j) op[j] = acc[j];
  }
}

// ---------------- GAT aggregate: per (dst node, channel) softmax + weighted sum, relu ----------------
__global__ __launch_bounds__(256) void k_gat_agg(const float* __restrict__ h, const int* __restrict__ rp,
                                                 const int* __restrict__ col, const float* __restrict__ al,
                                                 const float* __restrict__ ar, float* __restrict__ out, int n) {
  int node = blockIdx.x * 2 + (threadIdx.x >> 7);
  int ch = threadIdx.x & 127;
  if (node >= n) return;
  float alc = al[ch];
  float hr = h[node * DD + ch];
  float base = ar[ch] * hr;           // dst-side term (softmax-shift exact vs reference)
  int beg = rp[node], end = rp[node + 1];
  float num = 0.f, den = 0.f;
  for (int j = beg; j < end; ++j) {
    int s = col[j];
    float hs = h[s * DD + ch];
    float w = __expf(fmaf(alc, hs, base));
    den += w;
    num = fmaf(w, hs, num);
  }
  float o = num / (den + 1e-16f);
  out[node * DD + ch] = fmaxf(o, 0.f);
}

// ---------------- fused final: h@Wp1^T+bp1 -> @Wp2^T+bp2 -> log_softmax ----------------
__global__ __launch_bounds__(256) void k_final(const float* __restrict__ h, const float* __restrict__ Wp1,
                                               const float* __restrict__ bp1, const float* __restrict__ Wp2,
                                               const float* __restrict__ bp2, float* __restrict__ out, int n) {
  __shared__ float hT[32][257];
  int t = threadIdx.x;
  int node0 = blockIdx.x * 256;
  int node = node0 + t;
  float tacc[64];
#pragma unroll
  for (int o = 0; o < 64; ++o) tacc[o] = bp1[o];
  for (int k0 = 0; k0 < DD; k0 += 32) {
    __syncthreads();
#pragma unroll
    for (int i = 0; i < 32; ++i) {
      int flat = i * 256 + t;
      int kl = flat & 31, nn = flat >> 5;
      int nd = node0 + nn;
      hT[kl][nn] = (nd < n) ? h[nd * DD + k0 + kl] : 0.f;
    }
    __syncthreads();
    float hv[32];
#pragma unroll
    for (int kk = 0; kk < 32; ++kk) hv[kk] = hT[kk][t];
#pragma unroll
    for (int o = 0; o < 64; ++o) {
      const float* wr = Wp1 + o * DD + k0;   // truly uniform -> scalar loads
#pragma unroll
      for (int kk = 0; kk < 32; ++kk)
        tacc[o] = fmaf(hv[kk], wr[kk], tacc[o]);
    }
  }
  float u[OUTC];
  float m = -1e30f;
#pragma unroll
  for (int o2 = 0; o2 < OUTC; ++o2) {
    float a = bp2[o2];
    const float* wr = Wp2 + o2 * 64;
#pragma unroll
    for (int o = 0; o < 64; ++o) a = fmaf(tacc[o], wr[o], a);
    u[o2] = a;
    m = fmaxf(m, a);
  }
  float ssum = 0.f;
#pragma unroll
  for (int o2 = 0; o2 < OUTC; ++o2) ssum += __expf(u[o2] - m);
  float ls = __logf(ssum);
  if (node < n) {
    float* op = out + node * OUTC;
#pragma unroll
    for (int o2 = 0; o2 < OUTC; ++o2) op[o2] = u[o2] - m - ls;
  }
}

extern "C" void kernel_launch(void* const* d_in, const int* in_sizes, int n_in,
                              void* d_out, int out_size, void* d_ws, size_t ws_size,
                              hipStream_t stream) {
  const float* x   = (const float*)d_in[0];
  const int*   ei  = (const int*)d_in[1];
  const float* W[3]  = {(const float*)d_in[2],  (const float*)d_in[6],  (const float*)d_in[10]};
  const float* B[3]  = {(const float*)d_in[3],  (const float*)d_in[7],  (const float*)d_in[11]};
  const float* AL[3] = {(const float*)d_in[4],  (const float*)d_in[8],  (const float*)d_in[12]};
  const float* AR[3] = {(const float*)d_in[5],  (const float*)d_in[9],  (const float*)d_in[13]};
  const float* Wp1 = (const float*)d_in[14];
  const float* bp1 = (const float*)d_in[15];
  const float* Wp2 = (const float*)d_in[16];
  const float* bp2 = (const float*)d_in[17];
  float* outp = (float*)d_out;

  const int n = NN, e = EE;
  const int* srcp = ei;
  const int* dstp = ei + e;

  char* ws = (char*)d_ws;
  size_t off = 0;
  auto alloc = [&](size_t bytes) { void* p = ws + off; off = (off + bytes + 255) & ~(size_t)255; return p; };
  float* bufA  = (float*)alloc((size_t)n * DD * 4);
  float* bufB  = (float*)alloc((size_t)n * DD * 4);
  int*   deg   = (int*)alloc((size_t)n * 4);
  int*   rp    = (int*)alloc((size_t)(n + 1) * 4);
  int*   cursor= (int*)alloc((size_t)(n + 1) * 4);
  int*   bsum  = (int*)alloc(1024 * 4);
  int*   col   = (int*)alloc((size_t)e * 4);
  (void)ws_size;

  // CSR build (by dst)
  hipMemsetAsync(deg, 0, (size_t)n * 4, stream);
  k_hist<<<(e + 255) / 256, 256, 0, stream>>>(dstp, deg, e);
  int nb = (n + 1023) / 1024;
  k_scan1<<<nb, 1024, 0, stream>>>(deg, rp, bsum, n);
  k_scan2<<<1, 128, 0, stream>>>(bsum, nb);
  k_scan3<<<(n + 255) / 256, 256, 0, stream>>>(rp, bsum, cursor, n);
  k_scatter<<<(e + 255) / 256, 256, 0, stream>>>(srcp, dstp, cursor, col, e);

  // 3 GAT layers
  const float* cur = x;
  for (int l = 0; l < 3; ++l) {
    k_gemm128<<<(n + 127) / 128, 256, 0, stream>>>(cur, W[l], B[l], bufA, n);
    k_gat_agg<<<(n + 1) / 2, 256, 0, stream>>>(bufA, rp, col, AL[l], AR[l], bufB, n);
    cur = bufB;
  }

  // fused post-MLP + log_softmax
  k_final<<<(n + 255) / 256, 256, 0, stream>>>(bufB, Wp1, bp1, Wp2, bp2, outp, n);
}

// Round 2
// 765.881 us; speedup vs baseline: 1.8547x; 1.8547x over previous
//
#include <hip/hip_runtime.h>
#include <hip/hip_bf16.h>
#include <math.h>

#define NN 100000
#define EE 800000
#define DD 128
#define OUTC 40

// ---------------- CSR build ----------------
__global__ void k_hist(const int* __restrict__ dst, int* __restrict__ deg, int e) {
  int i = blockIdx.x * 256 + threadIdx.x;
  if (i < e) atomicAdd(&deg[dst[i]], 1);
}

__global__ __launch_bounds__(1024) void k_scan1(const int* __restrict__ deg, int* __restrict__ rp,
                                                int* __restrict__ bsum, int n) {
  __shared__ int s[1024];
  int t = threadIdx.x;
  int i = blockIdx.x * 1024 + t;
  s[t] = (i < n) ? deg[i] : 0;
  __syncthreads();
  for (int off = 1; off < 1024; off <<= 1) {
    int x = (t >= off) ? s[t - off] : 0;
    __syncthreads();
    s[t] += x;
    __syncthreads();
  }
  if (i < n) rp[i + 1] = s[t];
  if (t == 1023) bsum[blockIdx.x] = s[1023];
}

__global__ __launch_bounds__(128) void k_scan2(int* __restrict__ bsum, int nb) {
  __shared__ int s[128];
  int t = threadIdx.x;
  s[t] = (t < nb) ? bsum[t] : 0;
  __syncthreads();
  for (int off = 1; off < 128; off <<= 1) {
    int x = (t >= off) ? s[t - off] : 0;
    __syncthreads();
    s[t] += x;
    __syncthreads();
  }
  if (t < nb) bsum[t] = s[t];
}

__global__ void k_scan3(int* __restrict__ rp, const int* __restrict__ bsum,
                        int* __restrict__ cursor, int n) {
  int i = blockIdx.x * 256 + threadIdx.x;
  if (i == 0) { rp[0] = 0; cursor[0] = 0; }
  if (i < n) {
    int blk = i >> 10;
    int v = rp[i + 1] + ((blk > 0) ? bsum[blk - 1] : 0);
    rp[i + 1] = v;
    cursor[i + 1] = v;
  }
}

__global__ void k_scatter(const int* __restrict__ src, const int* __restrict__ dst,
                          int* __restrict__ cursor, int* __restrict__ col, int e) {
  int i = blockIdx.x * 256 + threadIdx.x;
  if (i < e) {
    int d = dst[i];
    int pos = atomicAdd(&cursor[d], 1);
    col[pos] = src[i];
  }
}

// ---------------- register-tiled f32 GEMM: out[n][o] = sum_k x[n][k]*W[o][k] + b[o] ----------------
// Block tile: 128 nodes x NOUT outs. 256 threads, thread tile 8 x (NOUT/16).
// K = DD = 128, staged in LDS in chunks of 16 with transposed+permuted layout.
template<int NOUT>
__global__ __launch_bounds__(256, 4) void k_gemm_t(const float* __restrict__ x,
                                                   const float* __restrict__ W,
                                                   const float* __restrict__ bias,
                                                   float* __restrict__ out, int n) {
  constexpr int KS = 16;
  constexpr int XROW = 192;                    // perm(127)=187
  constexpr int WROW = (NOUT == 128) ? 192 : 96;  // perm(63)=91
  constexpr int OPT = NOUT / 16;               // outs per thread (8 or 4)
  __shared__ float xs[KS][XROW];
  __shared__ float ws[KS][WROW];
  const int t = threadIdx.x;
  const int tn = t >> 4;     // node group 0..15 (8 nodes each)
  const int to = t & 15;     // out group 0..15 (OPT outs each) -> contiguous stores
  const int node0 = blockIdx.x * 128;

  float acc[8][OPT];
#pragma unroll
  for (int i = 0; i < 8; ++i)
#pragma unroll
    for (int j = 0; j < OPT; ++j) acc[i][j] = bias[to * OPT + j];

  for (int k0 = 0; k0 < DD; k0 += KS) {
    __syncthreads();
    // stage x tile: 128 nodes x 16 k
    {
      int nn = t >> 1;
      int kf = (t & 1) * 8;
      int node = node0 + nn;
      float4 a = make_float4(0.f, 0.f, 0.f, 0.f), b = a;
      if (node < n) {
        a = *(const float4*)&x[(size_t)node * DD + k0 + kf];
        b = *(const float4*)&x[(size_t)node * DD + k0 + kf + 4];
      }
      int pc = nn + ((nn >> 3) << 2);
      xs[kf + 0][pc] = a.x; xs[kf + 1][pc] = a.y; xs[kf + 2][pc] = a.z; xs[kf + 3][pc] = a.w;
      xs[kf + 4][pc] = b.x; xs[kf + 5][pc] = b.y; xs[kf + 6][pc] = b.z; xs[kf + 7][pc] = b.w;
    }
    // stage W tile: NOUT x 16 k
    if (NOUT == 128) {
      int oo = t >> 1;
      int kf = (t & 1) * 8;
      float4 a = *(const float4*)&W[(size_t)oo * DD + k0 + kf];
      float4 b = *(const float4*)&W[(size_t)oo * DD + k0 + kf + 4];
      int pc = oo + ((oo >> 3) << 2);
      ws[kf + 0][pc] = a.x; ws[kf + 1][pc] = a.y; ws[kf + 2][pc] = a.z; ws[kf + 3][pc] = a.w;
      ws[kf + 4][pc] = b.x; ws[kf + 5][pc] = b.y; ws[kf + 6][pc] = b.z; ws[kf + 7][pc] = b.w;
    } else {
      int oo = t >> 2;
      int kf = (t & 3) * 4;
      float4 a = *(const float4*)&W[(size_t)oo * DD + k0 + kf];
      int pc = oo + ((oo >> 3) << 2);
      ws[kf + 0][pc] = a.x; ws[kf + 1][pc] = a.y; ws[kf + 2][pc] = a.z; ws[kf + 3][pc] = a.w;
    }
    __syncthreads();
#pragma unroll
    for (int k = 0; k < KS; ++k) {
      float xv[8];
      *(float4*)&xv[0] = *(const float4*)&xs[k][12 * tn];
      *(float4*)&xv[4] = *(const float4*)&xs[k][12 * tn + 4];
      float wv[OPT];
      if (OPT == 8) {
        *(float4*)&wv[0] = *(const float4*)&ws[k][12 * to];
        *(float4*)&wv[4] = *(const float4*)&ws[k][12 * to + 4];
      } else {
        *(float4*)&wv[0] = *(const float4*)&ws[k][4 * to + ((to >> 1) << 2)];
      }
#pragma unroll
      for (int i = 0; i < 8; ++i)
#pragma unroll
        for (int j = 0; j < OPT; ++j)
          acc[i][j] = fmaf(xv[i], wv[j], acc[i][j]);
    }
  }
  // store
#pragma unroll
  for (int i = 0; i < 8; ++i) {
    int node = node0 + tn * 8 + i;
    if (node < n) {
      float* op = out + (size_t)node * NOUT + to * OPT;
#pragma unroll
      for (int j = 0; j < OPT; j += 4)
        *(float4*)&op[j] = make_float4(acc[i][j], acc[i][j + 1], acc[i][j + 2], acc[i][j + 3]);
    }
  }
}

// ---------------- GAT aggregate: per (dst node, channel) softmax + weighted sum, relu ----------------
__global__ __launch_bounds__(256) void k_gat_agg(const float* __restrict__ h, const int* __restrict__ rp,
                                                 const int* __restrict__ col, const float* __restrict__ al,
                                                 const float* __restrict__ ar, float* __restrict__ out, int n) {
  int node = blockIdx.x * 2 + (threadIdx.x >> 7);
  int ch = threadIdx.x & 127;
  if (node >= n) return;
  float alc = al[ch];
  float hr = h[(size_t)node * DD + ch];
  float base = ar[ch] * hr;           // dst-side term (softmax-shift exact vs reference)
  int beg = __builtin_amdgcn_readfirstlane(rp[node]);
  int end = __builtin_amdgcn_readfirstlane(rp[node + 1]);
  float num = 0.f, den = 0.f;
  for (int j = beg; j < end; ++j) {
    int s = __builtin_amdgcn_readfirstlane(col[j]);
    float hs = h[(size_t)s * DD + ch];
    float w = __expf(fmaf(alc, hs, base));
    den += w;
    num = fmaf(w, hs, num);
  }
  float o = num / (den + 1e-16f);
  out[(size_t)node * DD + ch] = fmaxf(o, 0.f);
}

// ---------------- final stage 2: logits = h1 @ Wp2^T + bp2 -> log_softmax ----------------
__global__ __launch_bounds__(256, 4) void k_fin2(const float* __restrict__ h1,
                                                 const float* __restrict__ Wp2,
                                                 const float* __restrict__ bp2,
                                                 float* __restrict__ out, int n) {
  int node = blockIdx.x * 256 + threadIdx.x;
  if (node >= n) return;
  float u[OUTC];
#pragma unroll
  for (int o = 0; o < OUTC; ++o) u[o] = bp2[o];
  const float* hp = h1 + (size_t)node * 64;
#pragma unroll
  for (int kc = 0; kc < 64; kc += 16) {
    float hv[16];
#pragma unroll
    for (int q = 0; q < 16; q += 4) *(float4*)&hv[q] = *(const float4*)&hp[kc + q];
#pragma unroll
    for (int o = 0; o < OUTC; ++o) {
      const float* wr = Wp2 + o * 64 + kc;   // uniform -> scalar loads
#pragma unroll
      for (int q = 0; q < 16; ++q) u[o] = fmaf(hv[q], wr[q], u[o]);
    }
  }
  float m = u[0];
#pragma unroll
  for (int o = 1; o < OUTC; ++o) m = fmaxf(m, u[o]);
  float ssum = 0.f;
#pragma unroll
  for (int o = 0; o < OUTC; ++o) ssum += __expf(u[o] - m);
  float ls = __logf(ssum) + m;
  float* op = out + (size_t)node * OUTC;
#pragma unroll
  for (int o = 0; o < OUTC; o += 4)
    *(float4*)&op[o] = make_float4(u[o] - ls, u[o + 1] - ls, u[o + 2] - ls, u[o + 3] - ls);
}

extern "C" void kernel_launch(void* const* d_in, const int* in_sizes, int n_in,
                              void* d_out, int out_size, void* d_ws, size_t ws_size,
                              hipStream_t stream) {
  const float* x   = (const float*)d_in[0];
  const int*   ei  = (const int*)d_in[1];
  const float* W[3]  = {(const float*)d_in[2],  (const float*)d_in[6],  (const float*)d_in[10]};
  const float* B[3]  = {(const float*)d_in[3],  (const float*)d_in[7],  (const float*)d_in[11]};
  const float* AL[3] = {(const float*)d_in[4],  (const float*)d_in[8],  (const float*)d_in[12]};
  const float* AR[3] = {(const float*)d_in[5],  (const float*)d_in[9],  (const float*)d_in[13]};
  const float* Wp1 = (const float*)d_in[14];
  const float* bp1 = (const float*)d_in[15];
  const float* Wp2 = (const float*)d_in[16];
  const float* bp2 = (const float*)d_in[17];
  float* outp = (float*)d_out;

  const int n = NN, e = EE;
  const int* srcp = ei;
  const int* dstp = ei + e;

  char* ws = (char*)d_ws;
  size_t off = 0;
  auto alloc = [&](size_t bytes) { void* p = ws + off; off = (off + bytes + 255) & ~(size_t)255; return p; };
  float* bufA  = (float*)alloc((size_t)n * DD * 4);
  float* bufB  = (float*)alloc((size_t)n * DD * 4);
  int*   deg   = (int*)alloc((size_t)n * 4);
  int*   rp    = (int*)alloc((size_t)(n + 1) * 4);
  int*   cursor= (int*)alloc((size_t)(n + 1) * 4);
  int*   bsum  = (int*)alloc(1024 * 4);
  int*   col   = (int*)alloc((size_t)e * 4);
  (void)ws_size;

  // CSR build (by dst)
  hipMemsetAsync(deg, 0, (size_t)n * 4, stream);
  k_hist<<<(e + 255) / 256, 256, 0, stream>>>(dstp, deg, e);
  int nb = (n + 1023) / 1024;
  k_scan1<<<nb, 1024, 0, stream>>>(deg, rp, bsum, n);
  k_scan2<<<1, 128, 0, stream>>>(bsum, nb);
  k_scan3<<<(n + 255) / 256, 256, 0, stream>>>(rp, bsum, cursor, n);
  k_scatter<<<(e + 255) / 256, 256, 0, stream>>>(srcp, dstp, cursor, col, e);

  // 3 GAT layers
  const int gblocks = (n + 127) / 128;
  const float* cur = x;
  for (int l = 0; l < 3; ++l) {
    k_gemm_t<128><<<gblocks, 256, 0, stream>>>(cur, W[l], B[l], bufA, n);
    k_gat_agg<<<(n + 1) / 2, 256, 0, stream>>>(bufA, rp, col, AL[l], AR[l], bufB, n);
    cur = bufB;
  }

  // final MLP: stage 1 (128->64) tiled GEMM into bufA, stage 2 (64->40) + log_softmax
  k_gemm_t<64><<<gblocks, 256, 0, stream>>>(bufB, Wp1, bp1, bufA, n);
  k_fin2<<<(n + 255) / 256, 256, 0, stream>>>(bufA, Wp2, bp2, outp, n);
}

// Round 3
// 431.876 us; speedup vs baseline: 3.2891x; 1.7734x over previous
//
#include <hip/hip_runtime.h>
#include <hip/hip_bf16.h>
#include <math.h>

#define NN 100000
#define EE 800000
#define DD 128
#define OUTC 40

typedef short bf16x8 __attribute__((ext_vector_type(8)));
typedef float f32x4 __attribute__((ext_vector_type(4)));

__device__ __forceinline__ ushort f2bf(float f) {
  unsigned u = __float_as_uint(f);
  u = (u + 0x7FFFu + ((u >> 16) & 1u)) >> 16;
  return (ushort)u;
}
__device__ __forceinline__ float bflo(unsigned u) { return __uint_as_float(u << 16); }
__device__ __forceinline__ float bfhi(unsigned u) { return __uint_as_float(u & 0xFFFF0000u); }

// swizzled byte offset for a [rows][256B] LDS tile (bank-conflict-free b128 col reads)
__device__ __forceinline__ int swz(int row, int kbyte) {
  return row * 256 + (kbyte ^ ((row & 7) << 4));
}

// ---------------- CSR build ----------------
__global__ void k_hist(const int* __restrict__ dst, int* __restrict__ deg, int e) {
  int i = blockIdx.x * 256 + threadIdx.x;
  if (i < e) atomicAdd(&deg[dst[i]], 1);
}

__global__ __launch_bounds__(1024) void k_scan1(const int* __restrict__ deg, int* __restrict__ rp,
                                                int* __restrict__ bsum, int n) {
  __shared__ int s[1024];
  int t = threadIdx.x;
  int i = blockIdx.x * 1024 + t;
  s[t] = (i < n) ? deg[i] : 0;
  __syncthreads();
  for (int off = 1; off < 1024; off <<= 1) {
    int x = (t >= off) ? s[t - off] : 0;
    __syncthreads();
    s[t] += x;
    __syncthreads();
  }
  if (i < n) rp[i + 1] = s[t];
  if (t == 1023) bsum[blockIdx.x] = s[1023];
}

__global__ __launch_bounds__(128) void k_scan2(int* __restrict__ bsum, int nb) {
  __shared__ int s[128];
  int t = threadIdx.x;
  s[t] = (t < nb) ? bsum[t] : 0;
  __syncthreads();
  for (int off = 1; off < 128; off <<= 1) {
    int x = (t >= off) ? s[t - off] : 0;
    __syncthreads();
    s[t] += x;
    __syncthreads();
  }
  if (t < nb) bsum[t] = s[t];
}

__global__ void k_scan3(int* __restrict__ rp, const int* __restrict__ bsum,
                        int* __restrict__ cursor, int n) {
  int i = blockIdx.x * 256 + threadIdx.x;
  if (i == 0) { rp[0] = 0; cursor[0] = 0; }
  if (i < n) {
    int blk = i >> 10;
    int v = rp[i + 1] + ((blk > 0) ? bsum[blk - 1] : 0);
    rp[i + 1] = v;
    cursor[i + 1] = v;
  }
}

__global__ void k_scatter(const int* __restrict__ src, const int* __restrict__ dst,
                          int* __restrict__ cursor, int* __restrict__ col, int e) {
  int i = blockIdx.x * 256 + threadIdx.x;
  if (i < e) {
    int d = dst[i];
    int pos = atomicAdd(&cursor[d], 1);
    col[pos] = src[i];
  }
}

// ---------------- MFMA bf16 GEMM: out[n][NOUT] = x[n][128] @ W[NOUT][128]^T + b ----------------
// 256 threads = 4 waves; block tile 128 nodes x NOUT. Full K=128 staged in LDS (bf16, swizzled).
// Wave w computes rows [32w, 32w+32), all NOUT cols: 2 row-tiles x NOUT/16 col-tiles.
template<int NOUT, bool INF32, bool OUTBF>
__global__ __launch_bounds__(256, 2) void k_mfma_gemm(const void* __restrict__ xin,
                                                      const float* __restrict__ W,
                                                      const float* __restrict__ bias,
                                                      void* __restrict__ outp, int n) {
  __shared__ __align__(16) char lds[32768 + NOUT * 256];
  const int t = threadIdx.x;
  const int node0 = blockIdx.x * 128;

  // ---- stage x tile (rows = 128 nodes, 256B bf16 rows) ----
  if (INF32) {
    // f32 input: 128 rows x 32 chunks(16B f32). 16 passes, coalesced.
#pragma unroll
    for (int p = 0; p < 16; ++p) {
      int F = p * 256 + t;
      int r = F >> 5, cchunk = F & 31;
      int node = node0 + r;
      float4 v = make_float4(0.f, 0.f, 0.f, 0.f);
      if (node < n) v = *(const float4*)((const float*)xin + (size_t)node * DD + cchunk * 4);
      ushort q[4] = {f2bf(v.x), f2bf(v.y), f2bf(v.z), f2bf(v.w)};
      *(unsigned long long*)(lds + swz(r, cchunk * 8)) = *(unsigned long long*)q;
    }
  } else {
    // bf16 input: 128 rows x 16 chunks(16B). 8 passes.
#pragma unroll
    for (int p = 0; p < 8; ++p) {
      int F = p * 256 + t;
      int r = F >> 4, cchunk = F & 15;
      int node = node0 + r;
      uint4 v = make_uint4(0u, 0u, 0u, 0u);
      if (node < n) v = *(const uint4*)((const ushort*)xin + (size_t)node * DD + cchunk * 8);
      *(uint4*)(lds + swz(r, cchunk * 16)) = v;
    }
  }
  // ---- stage W tile (NOUT rows, f32 -> bf16) ----
  {
    constexpr int WPASS = NOUT / 8;  // NOUT*32 chunks / 256 threads
#pragma unroll
    for (int p = 0; p < WPASS; ++p) {
      int F = p * 256 + t;
      int r = F >> 5, cchunk = F & 31;
      float4 v = *(const float4*)(W + (size_t)r * DD + cchunk * 4);
      ushort q[4] = {f2bf(v.x), f2bf(v.y), f2bf(v.z), f2bf(v.w)};
      *(unsigned long long*)(lds + 32768 + swz(r, cchunk * 8)) = *(unsigned long long*)q;
    }
  }
  __syncthreads();

  const int lane = t & 63;
  const int l15 = lane & 15;
  const int lkb = (lane >> 4) * 16;       // k-group byte offset within 64B chunk
  const int wrow0 = (t >> 6) * 32;
  constexpr int NJ = NOUT / 16;

  f32x4 acc[2][NJ];
#pragma unroll
  for (int j = 0; j < NJ; ++j) {
    float bv = bias[j * 16 + l15];
    acc[0][j] = (f32x4){bv, bv, bv, bv};
    acc[1][j] = (f32x4){bv, bv, bv, bv};
  }

#pragma unroll
  for (int c = 0; c < 4; ++c) {
    bf16x8 a0 = *(const bf16x8*)(lds + swz(wrow0 + l15, c * 64 + lkb));
    bf16x8 a1 = *(const bf16x8*)(lds + swz(wrow0 + 16 + l15, c * 64 + lkb));
#pragma unroll
    for (int j = 0; j < NJ; ++j) {
      bf16x8 b = *(const bf16x8*)(lds + 32768 + swz(j * 16 + l15, c * 64 + lkb));
      acc[0][j] = __builtin_amdgcn_mfma_f32_16x16x32_bf16(a0, b, acc[0][j], 0, 0, 0);
      acc[1][j] = __builtin_amdgcn_mfma_f32_16x16x32_bf16(a1, b, acc[1][j], 0, 0, 0);
    }
  }

  // ---- store: D col = l&15, row = 4*(l>>4)+reg ----
  const int rbase = wrow0 + (lane >> 4) * 4;
#pragma unroll
  for (int i = 0; i < 2; ++i) {
#pragma unroll
    for (int r = 0; r < 4; ++r) {
      int node = node0 + rbase + i * 16 + r;
      if (node < n) {
#pragma unroll
        for (int j = 0; j < NJ; ++j) {
          if (OUTBF)
            ((ushort*)outp)[(size_t)node * NOUT + j * 16 + l15] = f2bf(acc[i][j][r]);
          else
            ((float*)outp)[(size_t)node * NOUT + j * 16 + l15] = acc[i][j][r];
        }
      }
    }
  }
}

// ---------------- GAT aggregate (bf16 h): per (dst,ch) softmax + weighted sum, relu ----------------
// One wave per node; lane handles channels (2*lane, 2*lane+1). Edge loop unrolled x4 for MLP.
__global__ __launch_bounds__(256) void k_gat_agg(const ushort* __restrict__ h, const int* __restrict__ rp,
                                                 const int* __restrict__ col, const float* __restrict__ al,
                                                 const float* __restrict__ ar, ushort* __restrict__ out, int n) {
  int node = blockIdx.x * 4 + (threadIdx.x >> 6);
  int lane = threadIdx.x & 63;
  if (node >= n) return;
  const unsigned* hu = (const unsigned*)h;
  float al0 = al[2 * lane], al1 = al[2 * lane + 1];
  unsigned ud = hu[(unsigned)(node * 64 + lane)];
  float base0 = ar[2 * lane] * bflo(ud);
  float base1 = ar[2 * lane + 1] * bfhi(ud);
  int beg = __builtin_amdgcn_readfirstlane(rp[node]);
  int end = __builtin_amdgcn_readfirstlane(rp[node + 1]);
  float num0 = 0.f, num1 = 0.f, den0 = 0.f, den1 = 0.f;
#define ACCUM(U) { \
    float h0 = bflo(U), h1 = bfhi(U); \
    float w0 = __expf(fmaf(al0, h0, base0)); \
    float w1 = __expf(fmaf(al1, h1, base1)); \
    den0 += w0; den1 += w1; \
    num0 = fmaf(w0, h0, num0); num1 = fmaf(w1, h1, num1); }
  int j = beg;
  for (; j + 4 <= end; j += 4) {
    int s0 = __builtin_amdgcn_readfirstlane(col[j]);
    int s1 = __builtin_amdgcn_readfirstlane(col[j + 1]);
    int s2 = __builtin_amdgcn_readfirstlane(col[j + 2]);
    int s3 = __builtin_amdgcn_readfirstlane(col[j + 3]);
    unsigned u0 = hu[(unsigned)(s0 * 64 + lane)];
    unsigned u1 = hu[(unsigned)(s1 * 64 + lane)];
    unsigned u2 = hu[(unsigned)(s2 * 64 + lane)];
    unsigned u3 = hu[(unsigned)(s3 * 64 + lane)];
    ACCUM(u0); ACCUM(u1); ACCUM(u2); ACCUM(u3);
  }
  for (; j < end; ++j) {
    int s = __builtin_amdgcn_readfirstlane(col[j]);
    unsigned u = hu[(unsigned)(s * 64 + lane)];
    ACCUM(u);
  }
#undef ACCUM
  float o0 = fmaxf(num0 / (den0 + 1e-16f), 0.f);
  float o1 = fmaxf(num1 / (den1 + 1e-16f), 0.f);
  ((unsigned*)out)[(unsigned)(node * 64 + lane)] = (unsigned)f2bf(o0) | ((unsigned)f2bf(o1) << 16);
}

// ---------------- final stage 2: logits = h1 @ Wp2^T + bp2 -> log_softmax ----------------
__global__ __launch_bounds__(256, 4) void k_fin2(const float* __restrict__ h1,
                                                 const float* __restrict__ Wp2,
                                                 const float* __restrict__ bp2,
                                                 float* __restrict__ out, int n) {
  int node = blockIdx.x * 256 + threadIdx.x;
  if (node >= n) return;
  float u[OUTC];
#pragma unroll
  for (int o = 0; o < OUTC; ++o) u[o] = bp2[o];
  const float* hp = h1 + (size_t)node * 64;
#pragma unroll
  for (int kc = 0; kc < 64; kc += 16) {
    float hv[16];
#pragma unroll
    for (int q = 0; q < 16; q += 4) *(float4*)&hv[q] = *(const float4*)&hp[kc + q];
#pragma unroll
    for (int o = 0; o < OUTC; ++o) {
      const float* wr = Wp2 + o * 64 + kc;   // uniform -> scalar loads
#pragma unroll
      for (int q = 0; q < 16; ++q) u[o] = fmaf(hv[q], wr[q], u[o]);
    }
  }
  float m = u[0];
#pragma unroll
  for (int o = 1; o < OUTC; ++o) m = fmaxf(m, u[o]);
  float ssum = 0.f;
#pragma unroll
  for (int o = 0; o < OUTC; ++o) ssum += __expf(u[o] - m);
  float ls = __logf(ssum) + m;
  float* op = out + (size_t)node * OUTC;
#pragma unroll
  for (int o = 0; o < OUTC; o += 4)
    *(float4*)&op[o] = make_float4(u[o] - ls, u[o + 1] - ls, u[o + 2] - ls, u[o + 3] - ls);
}

extern "C" void kernel_launch(void* const* d_in, const int* in_sizes, int n_in,
                              void* d_out, int out_size, void* d_ws, size_t ws_size,
                              hipStream_t stream) {
  const float* x   = (const float*)d_in[0];
  const int*   ei  = (const int*)d_in[1];
  const float* W[3]  = {(const float*)d_in[2],  (const float*)d_in[6],  (const float*)d_in[10]};
  const float* B[3]  = {(const float*)d_in[3],  (const float*)d_in[7],  (const float*)d_in[11]};
  const float* AL[3] = {(const float*)d_in[4],  (const float*)d_in[8],  (const float*)d_in[12]};
  const float* AR[3] = {(const float*)d_in[5],  (const float*)d_in[9],  (const float*)d_in[13]};
  const float* Wp1 = (const float*)d_in[14];
  const float* bp1 = (const float*)d_in[15];
  const float* Wp2 = (const float*)d_in[16];
  const float* bp2 = (const float*)d_in[17];
  float* outp = (float*)d_out;

  const int n = NN, e = EE;
  const int* srcp = ei;
  const int* dstp = ei + e;

  char* ws = (char*)d_ws;
  size_t off = 0;
  auto alloc = [&](size_t bytes) { void* p = ws + off; off = (off + bytes + 255) & ~(size_t)255; return p; };
  ushort* bhA = (ushort*)alloc((size_t)n * DD * 2);   // bf16 h (pre-agg)
  ushort* bhB = (ushort*)alloc((size_t)n * DD * 2);   // bf16 h (post-agg)
  float*  h1f = (float*)alloc((size_t)n * 64 * 4);    // f32 Wp1 output
  int*   deg   = (int*)alloc((size_t)n * 4);
  int*   rp    = (int*)alloc((size_t)(n + 1) * 4);
  int*   cursor= (int*)alloc((size_t)(n + 1) * 4);
  int*   bsum  = (int*)alloc(1024 * 4);
  int*   col   = (int*)alloc((size_t)e * 4);
  (void)ws_size;

  // CSR build (by dst)
  hipMemsetAsync(deg, 0, (size_t)n * 4, stream);
  k_hist<<<(e + 255) / 256, 256, 0, stream>>>(dstp, deg, e);
  int nb = (n + 1023) / 1024;
  k_scan1<<<nb, 1024, 0, stream>>>(deg, rp, bsum, n);
  k_scan2<<<1, 128, 0, stream>>>(bsum, nb);
  k_scan3<<<(n + 255) / 256, 256, 0, stream>>>(rp, bsum, cursor, n);
  k_scatter<<<(e + 255) / 256, 256, 0, stream>>>(srcp, dstp, cursor, col, e);

  const int gblocks = (n + 127) / 128;
  const int ablocks = (n + 3) / 4;
  // layer 0: f32 x -> bf16 h
  k_mfma_gemm<128, true, true><<<gblocks, 256, 0, stream>>>(x, W[0], B[0], bhA, n);
  k_gat_agg<<<ablocks, 256, 0, stream>>>(bhA, rp, col, AL[0], AR[0], bhB, n);
  // layers 1,2: bf16 -> bf16
  for (int l = 1; l < 3; ++l) {
    k_mfma_gemm<128, false, true><<<gblocks, 256, 0, stream>>>(bhB, W[l], B[l], bhA, n);
    k_gat_agg<<<ablocks, 256, 0, stream>>>(bhA, rp, col, AL[l], AR[l], bhB, n);
  }
  // final MLP: Wp1 (128->64, f32 out) then Wp2 (64->40) + log_softmax
  k_mfma_gemm<64, false, false><<<gblocks, 256, 0, stream>>>(bhB, Wp1, bp1, h1f, n);
  k_fin2<<<(n + 255) / 256, 256, 0, stream>>>(h1f, Wp2, bp2, outp, n);
}

// Round 4
// 413.586 us; speedup vs baseline: 3.4346x; 1.0442x over previous
//
#include <hip/hip_runtime.h>
#include <hip/hip_bf16.h>
#include <math.h>

#define NN 100000
#define EE 800000
#define DD 128
#define OUTC 40

typedef short bf16x8 __attribute__((ext_vector_type(8)));
typedef float f32x4 __attribute__((ext_vector_type(4)));

__device__ __forceinline__ ushort f2bf(float f) {
  unsigned u = __float_as_uint(f);
  u = (u + 0x7FFFu + ((u >> 16) & 1u)) >> 16;
  return (ushort)u;
}
__device__ __forceinline__ float bflo(unsigned u) { return __uint_as_float(u << 16); }
__device__ __forceinline__ float bfhi(unsigned u) { return __uint_as_float(u & 0xFFFF0000u); }

// swizzled byte offset for a [rows][256B] LDS tile (bank-conflict-free b128 col reads)
__device__ __forceinline__ int swz(int row, int kbyte) {
  return row * 256 + (kbyte ^ ((row & 7) << 4));
}

// ---------------- CSR build ----------------
__global__ void k_hist(const int* __restrict__ dst, int* __restrict__ deg, int e) {
  int i = blockIdx.x * 256 + threadIdx.x;
  if (i < e) atomicAdd(&deg[dst[i]], 1);
}

__global__ __launch_bounds__(1024) void k_scan1(const int* __restrict__ deg, int* __restrict__ rp,
                                                int* __restrict__ bsum, int n) {
  __shared__ int s[1024];
  int t = threadIdx.x;
  int i = blockIdx.x * 1024 + t;
  s[t] = (i < n) ? deg[i] : 0;
  __syncthreads();
  for (int off = 1; off < 1024; off <<= 1) {
    int x = (t >= off) ? s[t - off] : 0;
    __syncthreads();
    s[t] += x;
    __syncthreads();
  }
  if (i < n) rp[i + 1] = s[t];
  if (t == 1023) bsum[blockIdx.x] = s[1023];
}

__global__ __launch_bounds__(128) void k_scan2(int* __restrict__ bsum, int nb) {
  __shared__ int s[128];
  int t = threadIdx.x;
  s[t] = (t < nb) ? bsum[t] : 0;
  __syncthreads();
  for (int off = 1; off < 128; off <<= 1) {
    int x = (t >= off) ? s[t - off] : 0;
    __syncthreads();
    s[t] += x;
    __syncthreads();
  }
  if (t < nb) bsum[t] = s[t];
}

__global__ void k_scan3(int* __restrict__ rp, const int* __restrict__ bsum,
                        int* __restrict__ cursor, int n) {
  int i = blockIdx.x * 256 + threadIdx.x;
  if (i == 0) { rp[0] = 0; cursor[0] = 0; }
  if (i < n) {
    int blk = i >> 10;
    int v = rp[i + 1] + ((blk > 0) ? bsum[blk - 1] : 0);
    rp[i + 1] = v;
    cursor[i + 1] = v;
  }
}

__global__ void k_scatter(const int* __restrict__ src, const int* __restrict__ dst,
                          int* __restrict__ cursor, int* __restrict__ col, int e) {
  int i = blockIdx.x * 256 + threadIdx.x;
  if (i < e) {
    int d = dst[i];
    int pos = atomicAdd(&cursor[d], 1);
    col[pos] = src[i];
  }
}

// ---------------- MFMA bf16 GEMM: out[n][128] = x[n][128] @ W[128][128]^T + b ----------------
template<bool INF32>
__global__ __launch_bounds__(256, 2) void k_mfma_gemm(const void* __restrict__ xin,
                                                      const float* __restrict__ W,
                                                      const float* __restrict__ bias,
                                                      ushort* __restrict__ outp, int n) {
  __shared__ __align__(16) char lds[65536];
  const int t = threadIdx.x;
  const int node0 = blockIdx.x * 128;

  if (INF32) {
#pragma unroll
    for (int p = 0; p < 16; ++p) {
      int F = p * 256 + t;
      int r = F >> 5, cchunk = F & 31;
      int node = node0 + r;
      float4 v = make_float4(0.f, 0.f, 0.f, 0.f);
      if (node < n) v = *(const float4*)((const float*)xin + (size_t)node * DD + cchunk * 4);
      ushort q[4] = {f2bf(v.x), f2bf(v.y), f2bf(v.z), f2bf(v.w)};
      *(unsigned long long*)(lds + swz(r, cchunk * 8)) = *(unsigned long long*)q;
    }
  } else {
#pragma unroll
    for (int p = 0; p < 8; ++p) {
      int F = p * 256 + t;
      int r = F >> 4, cchunk = F & 15;
      int node = node0 + r;
      uint4 v = make_uint4(0u, 0u, 0u, 0u);
      if (node < n) v = *(const uint4*)((const ushort*)xin + (size_t)node * DD + cchunk * 8);
      *(uint4*)(lds + swz(r, cchunk * 16)) = v;
    }
  }
  {
#pragma unroll
    for (int p = 0; p < 16; ++p) {
      int F = p * 256 + t;
      int r = F >> 5, cchunk = F & 31;
      float4 v = *(const float4*)(W + (size_t)r * DD + cchunk * 4);
      ushort q[4] = {f2bf(v.x), f2bf(v.y), f2bf(v.z), f2bf(v.w)};
      *(unsigned long long*)(lds + 32768 + swz(r, cchunk * 8)) = *(unsigned long long*)q;
    }
  }
  __syncthreads();

  const int lane = t & 63;
  const int l15 = lane & 15;
  const int lkb = (lane >> 4) * 16;
  const int wrow0 = (t >> 6) * 32;

  f32x4 acc[2][8];
#pragma unroll
  for (int j = 0; j < 8; ++j) {
    float bv = bias[j * 16 + l15];
    acc[0][j] = (f32x4){bv, bv, bv, bv};
    acc[1][j] = (f32x4){bv, bv, bv, bv};
  }

#pragma unroll
  for (int c = 0; c < 4; ++c) {
    bf16x8 a0 = *(const bf16x8*)(lds + swz(wrow0 + l15, c * 64 + lkb));
    bf16x8 a1 = *(const bf16x8*)(lds + swz(wrow0 + 16 + l15, c * 64 + lkb));
#pragma unroll
    for (int j = 0; j < 8; ++j) {
      bf16x8 b = *(const bf16x8*)(lds + 32768 + swz(j * 16 + l15, c * 64 + lkb));
      acc[0][j] = __builtin_amdgcn_mfma_f32_16x16x32_bf16(a0, b, acc[0][j], 0, 0, 0);
      acc[1][j] = __builtin_amdgcn_mfma_f32_16x16x32_bf16(a1, b, acc[1][j], 0, 0, 0);
    }
  }

  const int rbase = wrow0 + (lane >> 4) * 4;
#pragma unroll
  for (int i = 0; i < 2; ++i) {
#pragma unroll
    for (int r = 0; r < 4; ++r) {
      int node = node0 + rbase + i * 16 + r;
      if (node < n) {
#pragma unroll
        for (int j = 0; j < 8; ++j)
          outp[(size_t)node * DD + j * 16 + l15] = f2bf(acc[i][j][r]);
      }
    }
  }
}

// ---------------- GAT aggregate (bf16 h): per (dst,ch) softmax + weighted sum, relu ----------------
__global__ __launch_bounds__(256) void k_gat_agg(const ushort* __restrict__ h, const int* __restrict__ rp,
                                                 const int* __restrict__ col, const float* __restrict__ al,
                                                 const float* __restrict__ ar, ushort* __restrict__ out, int n) {
  int node = blockIdx.x * 4 + (threadIdx.x >> 6);
  int lane = threadIdx.x & 63;
  if (node >= n) return;
  const unsigned* hu = (const unsigned*)h;
  float al0 = al[2 * lane], al1 = al[2 * lane + 1];
  unsigned ud = hu[(unsigned)(node * 64 + lane)];
  float base0 = ar[2 * lane] * bflo(ud);
  float base1 = ar[2 * lane + 1] * bfhi(ud);
  int beg = __builtin_amdgcn_readfirstlane(rp[node]);
  int end = __builtin_amdgcn_readfirstlane(rp[node + 1]);
  float num0 = 0.f, num1 = 0.f, den0 = 0.f, den1 = 0.f;
#define ACCUM(U) { \
    float h0 = bflo(U), h1 = bfhi(U); \
    float w0 = __expf(fmaf(al0, h0, base0)); \
    float w1 = __expf(fmaf(al1, h1, base1)); \
    den0 += w0; den1 += w1; \
    num0 = fmaf(w0, h0, num0); num1 = fmaf(w1, h1, num1); }
  int j = beg;
  for (; j + 8 <= end; j += 8) {
    int s0 = __builtin_amdgcn_readfirstlane(col[j]);
    int s1 = __builtin_amdgcn_readfirstlane(col[j + 1]);
    int s2 = __builtin_amdgcn_readfirstlane(col[j + 2]);
    int s3 = __builtin_amdgcn_readfirstlane(col[j + 3]);
    int s4 = __builtin_amdgcn_readfirstlane(col[j + 4]);
    int s5 = __builtin_amdgcn_readfirstlane(col[j + 5]);
    int s6 = __builtin_amdgcn_readfirstlane(col[j + 6]);
    int s7 = __builtin_amdgcn_readfirstlane(col[j + 7]);
    unsigned u0 = hu[(unsigned)(s0 * 64 + lane)];
    unsigned u1 = hu[(unsigned)(s1 * 64 + lane)];
    unsigned u2 = hu[(unsigned)(s2 * 64 + lane)];
    unsigned u3 = hu[(unsigned)(s3 * 64 + lane)];
    unsigned u4 = hu[(unsigned)(s4 * 64 + lane)];
    unsigned u5 = hu[(unsigned)(s5 * 64 + lane)];
    unsigned u6 = hu[(unsigned)(s6 * 64 + lane)];
    unsigned u7 = hu[(unsigned)(s7 * 64 + lane)];
    ACCUM(u0); ACCUM(u1); ACCUM(u2); ACCUM(u3);
    ACCUM(u4); ACCUM(u5); ACCUM(u6); ACCUM(u7);
  }
  for (; j + 4 <= end; j += 4) {
    int s0 = __builtin_amdgcn_readfirstlane(col[j]);
    int s1 = __builtin_amdgcn_readfirstlane(col[j + 1]);
    int s2 = __builtin_amdgcn_readfirstlane(col[j + 2]);
    int s3 = __builtin_amdgcn_readfirstlane(col[j + 3]);
    unsigned u0 = hu[(unsigned)(s0 * 64 + lane)];
    unsigned u1 = hu[(unsigned)(s1 * 64 + lane)];
    unsigned u2 = hu[(unsigned)(s2 * 64 + lane)];
    unsigned u3 = hu[(unsigned)(s3 * 64 + lane)];
    ACCUM(u0); ACCUM(u1); ACCUM(u2); ACCUM(u3);
  }
  for (; j + 2 <= end; j += 2) {
    int s0 = __builtin_amdgcn_readfirstlane(col[j]);
    int s1 = __builtin_amdgcn_readfirstlane(col[j + 1]);
    unsigned u0 = hu[(unsigned)(s0 * 64 + lane)];
    unsigned u1 = hu[(unsigned)(s1 * 64 + lane)];
    ACCUM(u0); ACCUM(u1);
  }
  for (; j < end; ++j) {
    int s = __builtin_amdgcn_readfirstlane(col[j]);
    unsigned u = hu[(unsigned)(s * 64 + lane)];
    ACCUM(u);
  }
#undef ACCUM
  float o0 = fmaxf(num0 / (den0 + 1e-16f), 0.f);
  float o1 = fmaxf(num1 / (den1 + 1e-16f), 0.f);
  ((unsigned*)out)[(unsigned)(node * 64 + lane)] = (unsigned)f2bf(o0) | ((unsigned)f2bf(o1) << 16);
}

// ---------------- fused final: h@Wp1^T+bp1 (MFMA) -> LDS -> @Wp2^T+bp2 -> log_softmax ----------------
__global__ __launch_bounds__(256, 2) void k_final_fused(const ushort* __restrict__ xin,
                                                        const float* __restrict__ W1,
                                                        const float* __restrict__ b1,
                                                        const float* __restrict__ Wp2,
                                                        const float* __restrict__ bp2,
                                                        float* __restrict__ out, int n) {
  __shared__ __align__(16) char lds[49152];
  const int t = threadIdx.x;
  const int node0 = blockIdx.x * 128;

  // stage x (bf16) 128x128
#pragma unroll
  for (int p = 0; p < 8; ++p) {
    int F = p * 256 + t;
    int r = F >> 4, cchunk = F & 15;
    int node = node0 + r;
    uint4 v = make_uint4(0u, 0u, 0u, 0u);
    if (node < n) v = *(const uint4*)(xin + (size_t)node * DD + cchunk * 8);
    *(uint4*)(lds + swz(r, cchunk * 16)) = v;
  }
  // stage W1 (64 x 128, f32->bf16) at +32768
#pragma unroll
  for (int p = 0; p < 8; ++p) {
    int F = p * 256 + t;
    int r = F >> 5, cchunk = F & 31;
    float4 v = *(const float4*)(W1 + (size_t)r * DD + cchunk * 4);
    ushort q[4] = {f2bf(v.x), f2bf(v.y), f2bf(v.z), f2bf(v.w)};
    *(unsigned long long*)(lds + 32768 + swz(r, cchunk * 8)) = *(unsigned long long*)q;
  }
  __syncthreads();

  const int lane = t & 63;
  const int l15 = lane & 15;
  const int lkb = (lane >> 4) * 16;
  const int wrow0 = (t >> 6) * 32;

  f32x4 acc[2][4];
#pragma unroll
  for (int j = 0; j < 4; ++j) {
    float bv = b1[j * 16 + l15];
    acc[0][j] = (f32x4){bv, bv, bv, bv};
    acc[1][j] = (f32x4){bv, bv, bv, bv};
  }
#pragma unroll
  for (int c = 0; c < 4; ++c) {
    bf16x8 a0 = *(const bf16x8*)(lds + swz(wrow0 + l15, c * 64 + lkb));
    bf16x8 a1 = *(const bf16x8*)(lds + swz(wrow0 + 16 + l15, c * 64 + lkb));
#pragma unroll
    for (int j = 0; j < 4; ++j) {
      bf16x8 b = *(const bf16x8*)(lds + 32768 + swz(j * 16 + l15, c * 64 + lkb));
      acc[0][j] = __builtin_amdgcn_mfma_f32_16x16x32_bf16(a0, b, acc[0][j], 0, 0, 0);
      acc[1][j] = __builtin_amdgcn_mfma_f32_16x16x32_bf16(a1, b, acc[1][j], 0, 0, 0);
    }
  }
  __syncthreads();   // xs/ws no longer needed

  float* h1L = (float*)lds;                 // [128][68] = 34816 B
  float* wpL = (float*)(lds + 34816);       // [40][68]  = 10880 B
  const int rbase = wrow0 + (lane >> 4) * 4;
#pragma unroll
  for (int i = 0; i < 2; ++i)
#pragma unroll
    for (int r = 0; r < 4; ++r) {
      int row = rbase + i * 16 + r;
#pragma unroll
      for (int j = 0; j < 4; ++j)
        h1L[row * 68 + j * 16 + l15] = acc[i][j][r];
    }
  // stage Wp2 (40x64 f32)
#pragma unroll
  for (int p = 0; p < 10; ++p) {
    int f = p * 256 + t;
    int o = f >> 6, q = f & 63;
    wpL[o * 68 + q] = Wp2[f];
  }
  __syncthreads();

  if (t < 128) {
    int node = node0 + t;
    if (node < n) {
      float u[OUTC];
#pragma unroll
      for (int o = 0; o < OUTC; ++o) u[o] = bp2[o];
#pragma unroll
      for (int qc = 0; qc < 16; ++qc) {
        f32x4 hv = *(const f32x4*)&h1L[t * 68 + qc * 4];
#pragma unroll
        for (int o = 0; o < OUTC; ++o) {
          f32x4 w = *(const f32x4*)&wpL[o * 68 + qc * 4];   // wave-uniform addr -> broadcast
          u[o] = fmaf(hv[3], w[3], fmaf(hv[2], w[2], fmaf(hv[1], w[1], fmaf(hv[0], w[0], u[o]))));
        }
      }
      float m = u[0];
#pragma unroll
      for (int o = 1; o < OUTC; ++o) m = fmaxf(m, u[o]);
      float ssum = 0.f;
#pragma unroll
      for (int o = 0; o < OUTC; ++o) ssum += __expf(u[o] - m);
      float ls = __logf(ssum) + m;
      float* op = out + (size_t)node * OUTC;
#pragma unroll
      for (int o = 0; o < OUTC; o += 4)
        *(float4*)&op[o] = make_float4(u[o] - ls, u[o + 1] - ls, u[o + 2] - ls, u[o + 3] - ls);
    }
  }
}

extern "C" void kernel_launch(void* const* d_in, const int* in_sizes, int n_in,
                              void* d_out, int out_size, void* d_ws, size_t ws_size,
                              hipStream_t stream) {
  const float* x   = (const float*)d_in[0];
  const int*   ei  = (const int*)d_in[1];
  const float* W[3]  = {(const float*)d_in[2],  (const float*)d_in[6],  (const float*)d_in[10]};
  const float* B[3]  = {(const float*)d_in[3],  (const float*)d_in[7],  (const float*)d_in[11]};
  const float* AL[3] = {(const float*)d_in[4],  (const float*)d_in[8],  (const float*)d_in[12]};
  const float* AR[3] = {(const float*)d_in[5],  (const float*)d_in[9],  (const float*)d_in[13]};
  const float* Wp1 = (const float*)d_in[14];
  const float* bp1 = (const float*)d_in[15];
  const float* Wp2 = (const float*)d_in[16];
  const float* bp2 = (const float*)d_in[17];
  float* outp = (float*)d_out;

  const int n = NN, e = EE;
  const int* srcp = ei;
  const int* dstp = ei + e;

  char* ws = (char*)d_ws;
  size_t off = 0;
  auto alloc = [&](size_t bytes) { void* p = ws + off; off = (off + bytes + 255) & ~(size_t)255; return p; };
  ushort* bhA = (ushort*)alloc((size_t)n * DD * 2);   // bf16 h (pre-agg)
  ushort* bhB = (ushort*)alloc((size_t)n * DD * 2);   // bf16 h (post-agg)
  int*   deg   = (int*)alloc((size_t)n * 4);
  int*   rp    = (int*)alloc((size_t)(n + 1) * 4);
  int*   cursor= (int*)alloc((size_t)(n + 1) * 4);
  int*   bsum  = (int*)alloc(1024 * 4);
  int*   col   = (int*)alloc((size_t)e * 4);
  (void)ws_size;

  // CSR build (by dst)
  hipMemsetAsync(deg, 0, (size_t)n * 4, stream);
  k_hist<<<(e + 255) / 256, 256, 0, stream>>>(dstp, deg, e);
  int nb = (n + 1023) / 1024;
  k_scan1<<<nb, 1024, 0, stream>>>(deg, rp, bsum, n);
  k_scan2<<<1, 128, 0, stream>>>(bsum, nb);
  k_scan3<<<(n + 255) / 256, 256, 0, stream>>>(rp, bsum, cursor, n);
  k_scatter<<<(e + 255) / 256, 256, 0, stream>>>(srcp, dstp, cursor, col, e);

  const int gblocks = (n + 127) / 128;
  const int ablocks = (n + 3) / 4;
  // layer 0: f32 x -> bf16 h
  k_mfma_gemm<true><<<gblocks, 256, 0, stream>>>(x, W[0], B[0], bhA, n);
  k_gat_agg<<<ablocks, 256, 0, stream>>>(bhA, rp, col, AL[0], AR[0], bhB, n);
  // layers 1,2: bf16 -> bf16
  for (int l = 1; l < 3; ++l) {
    k_mfma_gemm<false><<<gblocks, 256, 0, stream>>>(bhB, W[l], B[l], bhA, n);
    k_gat_agg<<<ablocks, 256, 0, stream>>>(bhA, rp, col, AL[l], AR[l], bhB, n);
  }
  // fused final MLP + log_softmax
  k_final_fused<<<gblocks, 256, 0, stream>>>(bhB, Wp1, bp1, Wp2, bp2, outp, n);
}

// Round 6
// 375.616 us; speedup vs baseline: 3.7818x; 1.1011x over previous
//
#include <hip/hip_runtime.h>
#include <hip/hip_bf16.h>
#include <math.h>

#define NN 100000
#define EE 800000
#define DD 128
#define OUTC 40

constexpr int NBUCK = (NN + 511) >> 9;   // 196 buckets of 512 nodes
constexpr int BCAP  = 6144;              // per-bucket capacity (mean 4082, sd 64)
constexpr int EB    = 8192;              // edges per binning block

typedef short bf16x8 __attribute__((ext_vector_type(8)));
typedef float f32x4 __attribute__((ext_vector_type(4)));

__device__ __forceinline__ ushort f2bf(float f) {
  unsigned u = __float_as_uint(f);
  u = (u + 0x7FFFu + ((u >> 16) & 1u)) >> 16;
  return (ushort)u;
}
__device__ __forceinline__ float bflo(unsigned u) { return __uint_as_float(u << 16); }
__device__ __forceinline__ float bfhi(unsigned u) { return __uint_as_float(u & 0xFFFF0000u); }

// swizzled byte offset for a [rows][256B] LDS tile (bank-conflict-free b128 col reads)
__device__ __forceinline__ int swz(int row, int kbyte) {
  return row * 256 + (kbyte ^ ((row & 7) << 4));
}

// ---------------- CSR build via bucket binning ----------------
__global__ __launch_bounds__(256) void k_initcur(int* __restrict__ cursor0) {
  int b = threadIdx.x;
  if (b < NBUCK) cursor0[b] = b * BCAP;
}

__global__ __launch_bounds__(256) void k_binA(const int* __restrict__ src, const int* __restrict__ dst,
                                              int* __restrict__ cursor0, int2* __restrict__ binned, int e) {
  __shared__ int cnt[NBUCK], base[NBUCK], cnt2[NBUCK];
  int t = threadIdx.x;
  for (int b = t; b < NBUCK; b += 256) { cnt[b] = 0; cnt2[b] = 0; }
  __syncthreads();
  int e0 = blockIdx.x * EB;
#pragma unroll
  for (int p = 0; p < EB / 256; ++p) {
    int i = e0 + p * 256 + t;
    if (i < e) atomicAdd(&cnt[dst[i] >> 9], 1);
  }
  __syncthreads();
  for (int b = t; b < NBUCK; b += 256)
    if (cnt[b] > 0) base[b] = atomicAdd(&cursor0[b], cnt[b]);
  __syncthreads();
#pragma unroll
  for (int p = 0; p < EB / 256; ++p) {
    int i = e0 + p * 256 + t;
    if (i < e) {
      int d = dst[i];
      int bk = d >> 9;
      int pos = base[bk] + atomicAdd(&cnt2[bk], 1);
      binned[pos] = make_int2(src[i], d);
    }
  }
}

__global__ __launch_bounds__(256) void k_degB(const int* __restrict__ cursor0,
                                              const int2* __restrict__ binned,
                                              int* __restrict__ deg, int n) {
  __shared__ int cnt[512];
  int b = blockIdx.x, t = threadIdx.x;
  cnt[t] = 0; cnt[t + 256] = 0;
  __syncthreads();
  int node0 = b << 9;
  int beg = b * BCAP;
  int cend = cursor0[b];
  for (int i = beg + t; i < cend; i += 256)
    atomicAdd(&cnt[binned[i].y - node0], 1);
  __syncthreads();
  if (node0 + t < n) deg[node0 + t] = cnt[t];
  if (node0 + t + 256 < n) deg[node0 + t + 256] = cnt[t + 256];
}

__global__ __launch_bounds__(1024) void k_scan1(const int* __restrict__ deg, int* __restrict__ rp,
                                                int* __restrict__ bsum, int n) {
  __shared__ int s[1024];
  int t = threadIdx.x;
  int i = blockIdx.x * 1024 + t;
  s[t] = (i < n) ? deg[i] : 0;
  __syncthreads();
  for (int off = 1; off < 1024; off <<= 1) {
    int x = (t >= off) ? s[t - off] : 0;
    __syncthreads();
    s[t] += x;
    __syncthreads();
  }
  if (i < n) rp[i + 1] = s[t];
  if (t == 1023) bsum[blockIdx.x] = s[1023];
}

__global__ __launch_bounds__(128) void k_scan2(int* __restrict__ bsum, int nb) {
  __shared__ int s[128];
  int t = threadIdx.x;
  s[t] = (t < nb) ? bsum[t] : 0;
  __syncthreads();
  for (int off = 1; off < 128; off <<= 1) {
    int x = (t >= off) ? s[t - off] : 0;
    __syncthreads();
    s[t] += x;
    __syncthreads();
  }
  if (t < nb) bsum[t] = s[t];
}

__global__ void k_scan3(int* __restrict__ rp, const int* __restrict__ bsum, int n) {
  int i = blockIdx.x * 256 + threadIdx.x;
  if (i == 0) rp[0] = 0;
  if (i < n) {
    int blk = i >> 10;
    rp[i + 1] = rp[i + 1] + ((blk > 0) ? bsum[blk - 1] : 0);
  }
}

__global__ __launch_bounds__(256) void k_scatC(const int* __restrict__ cursor0,
                                               const int2* __restrict__ binned,
                                               const int* __restrict__ rp,
                                               int* __restrict__ col, int n) {
  __shared__ int cur[512];
  __shared__ int lrp[512];
  int b = blockIdx.x, t = threadIdx.x;
  cur[t] = 0; cur[t + 256] = 0;
  int node0 = b << 9;
  lrp[t] = (node0 + t < n) ? rp[node0 + t] : 0;
  lrp[t + 256] = (node0 + t + 256 < n) ? rp[node0 + t + 256] : 0;
  __syncthreads();
  int beg = b * BCAP;
  int cend = cursor0[b];
  for (int i = beg + t; i < cend; i += 256) {
    int2 p = binned[i];
    int d = p.y - node0;
    int pos = lrp[d] + atomicAdd(&cur[d], 1);
    col[pos] = p.x;
  }
}

// ---------------- MFMA bf16 GEMM: out[n][128] = x[n][128] @ W[128][128]^T + b ----------------
template<bool INF32>
__global__ __launch_bounds__(256, 2) void k_mfma_gemm(const void* __restrict__ xin,
                                                      const float* __restrict__ W,
                                                      const float* __restrict__ bias,
                                                      ushort* __restrict__ outp, int n) {
  __shared__ __align__(16) char lds[65536];
  const int t = threadIdx.x;
  const int node0 = blockIdx.x * 128;

  if (INF32) {
#pragma unroll
    for (int p = 0; p < 16; ++p) {
      int F = p * 256 + t;
      int r = F >> 5, cchunk = F & 31;
      int node = node0 + r;
      float4 v = make_float4(0.f, 0.f, 0.f, 0.f);
      if (node < n) v = *(const float4*)((const float*)xin + (size_t)node * DD + cchunk * 4);
      ushort q[4] = {f2bf(v.x), f2bf(v.y), f2bf(v.z), f2bf(v.w)};
      *(unsigned long long*)(lds + swz(r, cchunk * 8)) = *(unsigned long long*)q;
    }
  } else {
#pragma unroll
    for (int p = 0; p < 8; ++p) {
      int F = p * 256 + t;
      int r = F >> 4, cchunk = F & 15;
      int node = node0 + r;
      uint4 v = make_uint4(0u, 0u, 0u, 0u);
      if (node < n) v = *(const uint4*)((const ushort*)xin + (size_t)node * DD + cchunk * 8);
      *(uint4*)(lds + swz(r, cchunk * 16)) = v;
    }
  }
  {
#pragma unroll
    for (int p = 0; p < 16; ++p) {
      int F = p * 256 + t;
      int r = F >> 5, cchunk = F & 31;
      float4 v = *(const float4*)(W + (size_t)r * DD + cchunk * 4);
      ushort q[4] = {f2bf(v.x), f2bf(v.y), f2bf(v.z), f2bf(v.w)};
      *(unsigned long long*)(lds + 32768 + swz(r, cchunk * 8)) = *(unsigned long long*)q;
    }
  }
  __syncthreads();

  const int lane = t & 63;
  const int l15 = lane & 15;
  const int lkb = (lane >> 4) * 16;
  const int wrow0 = (t >> 6) * 32;

  f32x4 acc[2][8];
#pragma unroll
  for (int j = 0; j < 8; ++j) {
    float bv = bias[j * 16 + l15];
    acc[0][j] = (f32x4){bv, bv, bv, bv};
    acc[1][j] = (f32x4){bv, bv, bv, bv};
  }

#pragma unroll
  for (int c = 0; c < 4; ++c) {
    bf16x8 a0 = *(const bf16x8*)(lds + swz(wrow0 + l15, c * 64 + lkb));
    bf16x8 a1 = *(const bf16x8*)(lds + swz(wrow0 + 16 + l15, c * 64 + lkb));
#pragma unroll
    for (int j = 0; j < 8; ++j) {
      bf16x8 b = *(const bf16x8*)(lds + 32768 + swz(j * 16 + l15, c * 64 + lkb));
      acc[0][j] = __builtin_amdgcn_mfma_f32_16x16x32_bf16(a0, b, acc[0][j], 0, 0, 0);
      acc[1][j] = __builtin_amdgcn_mfma_f32_16x16x32_bf16(a1, b, acc[1][j], 0, 0, 0);
    }
  }

  const int rbase = wrow0 + (lane >> 4) * 4;
#pragma unroll
  for (int i = 0; i < 2; ++i) {
#pragma unroll
    for (int r = 0; r < 4; ++r) {
      int node = node0 + rbase + i * 16 + r;
      if (node < n) {
#pragma unroll
        for (int j = 0; j < 8; ++j)
          outp[(size_t)node * DD + j * 16 + l15] = f2bf(acc[i][j][r]);
      }
    }
  }
}

// ---------------- GAT aggregate (bf16 h): per (dst,ch) softmax + weighted sum, relu ----------------
__global__ __launch_bounds__(256) void k_gat_agg(const ushort* __restrict__ h, const int* __restrict__ rp,
                                                 const int* __restrict__ col, const float* __restrict__ al,
                                                 const float* __restrict__ ar, ushort* __restrict__ out, int n) {
  int node = blockIdx.x * 4 + (threadIdx.x >> 6);
  int lane = threadIdx.x & 63;
  if (node >= n) return;
  const unsigned* hu = (const unsigned*)h;
  float al0 = al[2 * lane], al1 = al[2 * lane + 1];
  unsigned ud = hu[(unsigned)(node * 64 + lane)];
  float base0 = ar[2 * lane] * bflo(ud);
  float base1 = ar[2 * lane + 1] * bfhi(ud);
  int beg = __builtin_amdgcn_readfirstlane(rp[node]);
  int end = __builtin_amdgcn_readfirstlane(rp[node + 1]);
  float num0 = 0.f, num1 = 0.f, den0 = 0.f, den1 = 0.f;
#define ACCUM(U) { \
    float h0 = bflo(U), h1 = bfhi(U); \
    float w0 = __expf(fmaf(al0, h0, base0)); \
    float w1 = __expf(fmaf(al1, h1, base1)); \
    den0 += w0; den1 += w1; \
    num0 = fmaf(w0, h0, num0); num1 = fmaf(w1, h1, num1); }
  int j = beg;
  for (; j + 8 <= end; j += 8) {
    int s0 = __builtin_amdgcn_readfirstlane(col[j]);
    int s1 = __builtin_amdgcn_readfirstlane(col[j + 1]);
    int s2 = __builtin_amdgcn_readfirstlane(col[j + 2]);
    int s3 = __builtin_amdgcn_readfirstlane(col[j + 3]);
    int s4 = __builtin_amdgcn_readfirstlane(col[j + 4]);
    int s5 = __builtin_amdgcn_readfirstlane(col[j + 5]);
    int s6 = __builtin_amdgcn_readfirstlane(col[j + 6]);
    int s7 = __builtin_amdgcn_readfirstlane(col[j + 7]);
    unsigned u0 = hu[(unsigned)(s0 * 64 + lane)];
    unsigned u1 = hu[(unsigned)(s1 * 64 + lane)];
    unsigned u2 = hu[(unsigned)(s2 * 64 + lane)];
    unsigned u3 = hu[(unsigned)(s3 * 64 + lane)];
    unsigned u4 = hu[(unsigned)(s4 * 64 + lane)];
    unsigned u5 = hu[(unsigned)(s5 * 64 + lane)];
    unsigned u6 = hu[(unsigned)(s6 * 64 + lane)];
    unsigned u7 = hu[(unsigned)(s7 * 64 + lane)];
    ACCUM(u0); ACCUM(u1); ACCUM(u2); ACCUM(u3);
    ACCUM(u4); ACCUM(u5); ACCUM(u6); ACCUM(u7);
  }
  for (; j + 4 <= end; j += 4) {
    int s0 = __builtin_amdgcn_readfirstlane(col[j]);
    int s1 = __builtin_amdgcn_readfirstlane(col[j + 1]);
    int s2 = __builtin_amdgcn_readfirstlane(col[j + 2]);
    int s3 = __builtin_amdgcn_readfirstlane(col[j + 3]);
    unsigned u0 = hu[(unsigned)(s0 * 64 + lane)];
    unsigned u1 = hu[(unsigned)(s1 * 64 + lane)];
    unsigned u2 = hu[(unsigned)(s2 * 64 + lane)];
    unsigned u3 = hu[(unsigned)(s3 * 64 + lane)];
    ACCUM(u0); ACCUM(u1); ACCUM(u2); ACCUM(u3);
  }
  for (; j + 2 <= end; j += 2) {
    int s0 = __builtin_amdgcn_readfirstlane(col[j]);
    int s1 = __builtin_amdgcn_readfirstlane(col[j + 1]);
    unsigned u0 = hu[(unsigned)(s0 * 64 + lane)];
    unsigned u1 = hu[(unsigned)(s1 * 64 + lane)];
    ACCUM(u0); ACCUM(u1);
  }
  for (; j < end; ++j) {
    int s = __builtin_amdgcn_readfirstlane(col[j]);
    unsigned u = hu[(unsigned)(s * 64 + lane)];
    ACCUM(u);
  }
#undef ACCUM
  float o0 = fmaxf(num0 / (den0 + 1e-16f), 0.f);
  float o1 = fmaxf(num1 / (den1 + 1e-16f), 0.f);
  ((unsigned*)out)[(unsigned)(node * 64 + lane)] = (unsigned)f2bf(o0) | ((unsigned)f2bf(o1) << 16);
}

// ---------------- fused final: h@Wp1^T+bp1 (MFMA) -> LDS -> @Wp2^T+bp2 -> log_softmax ----------------
__global__ __launch_bounds__(256, 2) void k_final_fused(const ushort* __restrict__ xin,
                                                        const float* __restrict__ W1,
                                                        const float* __restrict__ b1,
                                                        const float* __restrict__ Wp2,
                                                        const float* __restrict__ bp2,
                                                        float* __restrict__ out, int n) {
  __shared__ __align__(16) char lds[49152];
  const int t = threadIdx.x;
  const int node0 = blockIdx.x * 128;

#pragma unroll
  for (int p = 0; p < 8; ++p) {
    int F = p * 256 + t;
    int r = F >> 4, cchunk = F & 15;
    int node = node0 + r;
    uint4 v = make_uint4(0u, 0u, 0u, 0u);
    if (node < n) v = *(const uint4*)(xin + (size_t)node * DD + cchunk * 8);
    *(uint4*)(lds + swz(r, cchunk * 16)) = v;
  }
#pragma unroll
  for (int p = 0; p < 8; ++p) {
    int F = p * 256 + t;
    int r = F >> 5, cchunk = F & 31;
    float4 v = *(const float4*)(W1 + (size_t)r * DD + cchunk * 4);
    ushort q[4] = {f2bf(v.x), f2bf(v.y), f2bf(v.z), f2bf(v.w)};
    *(unsigned long long*)(lds + 32768 + swz(r, cchunk * 8)) = *(unsigned long long*)q;
  }
  __syncthreads();

  const int lane = t & 63;
  const int l15 = lane & 15;
  const int lkb = (lane >> 4) * 16;
  const int wrow0 = (t >> 6) * 32;

  f32x4 acc[2][4];
#pragma unroll
  for (int j = 0; j < 4; ++j) {
    float bv = b1[j * 16 + l15];
    acc[0][j] = (f32x4){bv, bv, bv, bv};
    acc[1][j] = (f32x4){bv, bv, bv, bv};
  }
#pragma unroll
  for (int c = 0; c < 4; ++c) {
    bf16x8 a0 = *(const bf16x8*)(lds + swz(wrow0 + l15, c * 64 + lkb));
    bf16x8 a1 = *(const bf16x8*)(lds + swz(wrow0 + 16 + l15, c * 64 + lkb));
#pragma unroll
    for (int j = 0; j < 4; ++j) {
      bf16x8 b = *(const bf16x8*)(lds + 32768 + swz(j * 16 + l15, c * 64 + lkb));
      acc[0][j] = __builtin_amdgcn_mfma_f32_16x16x32_bf16(a0, b, acc[0][j], 0, 0, 0);
      acc[1][j] = __builtin_amdgcn_mfma_f32_16x16x32_bf16(a1, b, acc[1][j], 0, 0, 0);
    }
  }
  __syncthreads();

  float* h1L = (float*)lds;                 // [128][68]
  float* wpL = (float*)(lds + 34816);       // [40][68]
  const int rbase = wrow0 + (lane >> 4) * 4;
#pragma unroll
  for (int i = 0; i < 2; ++i)
#pragma unroll
    for (int r = 0; r < 4; ++r) {
      int row = rbase + i * 16 + r;
#pragma unroll
      for (int j = 0; j < 4; ++j)
        h1L[row * 68 + j * 16 + l15] = acc[i][j][r];
    }
#pragma unroll
  for (int p = 0; p < 10; ++p) {
    int f = p * 256 + t;
    int o = f >> 6, q = f & 63;
    wpL[o * 68 + q] = Wp2[f];
  }
  __syncthreads();

  if (t < 128) {
    int node = node0 + t;
    if (node < n) {
      float u[OUTC];
#pragma unroll
      for (int o = 0; o < OUTC; ++o) u[o] = bp2[o];
#pragma unroll
      for (int qc = 0; qc < 16; ++qc) {
        f32x4 hv = *(const f32x4*)&h1L[t * 68 + qc * 4];
#pragma unroll
        for (int o = 0; o < OUTC; ++o) {
          f32x4 w = *(const f32x4*)&wpL[o * 68 + qc * 4];
          u[o] = fmaf(hv[3], w[3], fmaf(hv[2], w[2], fmaf(hv[1], w[1], fmaf(hv[0], w[0], u[o]))));
        }
      }
      float m = u[0];
#pragma unroll
      for (int o = 1; o < OUTC; ++o) m = fmaxf(m, u[o]);
      float ssum = 0.f;
#pragma unroll
      for (int o = 0; o < OUTC; ++o) ssum += __expf(u[o] - m);
      float ls = __logf(ssum) + m;
      float* op = out + (size_t)node * OUTC;
#pragma unroll
      for (int o = 0; o < OUTC; o += 4)
        *(float4*)&op[o] = make_float4(u[o] - ls, u[o + 1] - ls, u[o + 2] - ls, u[o + 3] - ls);
    }
  }
}

extern "C" void kernel_launch(void* const* d_in, const int* in_sizes, int n_in,
                              void* d_out, int out_size, void* d_ws, size_t ws_size,
                              hipStream_t stream) {
  const float* x   = (const float*)d_in[0];
  const int*   ei  = (const int*)d_in[1];
  const float* W[3]  = {(const float*)d_in[2],  (const float*)d_in[6],  (const float*)d_in[10]};
  const float* B[3]  = {(const float*)d_in[3],  (const float*)d_in[7],  (const float*)d_in[11]};
  const float* AL[3] = {(const float*)d_in[4],  (const float*)d_in[8],  (const float*)d_in[12]};
  const float* AR[3] = {(const float*)d_in[5],  (const float*)d_in[9],  (const float*)d_in[13]};
  const float* Wp1 = (const float*)d_in[14];
  const float* bp1 = (const float*)d_in[15];
  const float* Wp2 = (const float*)d_in[16];
  const float* bp2 = (const float*)d_in[17];
  float* outp = (float*)d_out;

  const int n = NN, e = EE;
  const int* srcp = ei;
  const int* dstp = ei + e;

  char* ws = (char*)d_ws;
  size_t off = 0;
  auto alloc = [&](size_t bytes) { void* p = ws + off; off = (off + bytes + 255) & ~(size_t)255; return p; };
  ushort* bhA = (ushort*)alloc((size_t)n * DD * 2);   // bf16 h (pre-agg)
  ushort* bhB = (ushort*)alloc((size_t)n * DD * 2);   // bf16 h (post-agg)
  int*   deg   = (int*)alloc((size_t)n * 4);
  int*   rp    = (int*)alloc((size_t)(n + 1) * 4);
  int*   bsum  = (int*)alloc(1024 * 4);
  int*   col   = (int*)alloc((size_t)e * 4);
  int*   cursor0 = (int*)alloc((size_t)NBUCK * 4);
  int2*  binned  = (int2*)alloc((size_t)NBUCK * BCAP * 8);
  (void)ws_size;

  // CSR build (by dst) via bucket binning — no random 4B scatters to HBM
  k_initcur<<<1, 256, 0, stream>>>(cursor0);
  k_binA<<<(e + EB - 1) / EB, 256, 0, stream>>>(srcp, dstp, cursor0, binned, e);
  k_degB<<<NBUCK, 256, 0, stream>>>(cursor0, binned, deg, n);
  int nb = (n + 1023) / 1024;
  k_scan1<<<nb, 1024, 0, stream>>>(deg, rp, bsum, n);
  k_scan2<<<1, 128, 0, stream>>>(bsum, nb);
  k_scan3<<<(n + 255) / 256, 256, 0, stream>>>(rp, bsum, n);
  k_scatC<<<NBUCK, 256, 0, stream>>>(cursor0, binned, rp, col, n);

  const int gblocks = (n + 127) / 128;
  const int ablocks = (n + 3) / 4;
  // layer 0: f32 x -> bf16 h
  k_mfma_gemm<true><<<gblocks, 256, 0, stream>>>(x, W[0], B[0], bhA, n);
  k_gat_agg<<<ablocks, 256, 0, stream>>>(bhA, rp, col, AL[0], AR[0], bhB, n);
  // layers 1,2: bf16 -> bf16
  for (int l = 1; l < 3; ++l) {
    k_mfma_gemm<false><<<gblocks, 256, 0, stream>>>(bhB, W[l], B[l], bhA, n);
    k_gat_agg<<<ablocks, 256, 0, stream>>>(bhA, rp, col, AL[l], AR[l], bhB, n);
  }
  // fused final MLP + log_softmax
  k_final_fused<<<gblocks, 256, 0, stream>>>(bhB, Wp1, bp1, Wp2, bp2, outp, n);
}

// Round 7
// 345.565 us; speedup vs baseline: 4.1107x; 1.0870x over previous
//
#include <hip/hip_runtime.h>
#include <hip/hip_bf16.h>
#include <math.h>

#define NN 100000
#define EE 800000
#define DD 128
#define OUTC 40

constexpr int NBUCK = (NN + 511) >> 9;   // 196 buckets of 512 nodes
constexpr int BCAP  = 6144;              // per-bucket capacity (mean 4082, sd 64)
constexpr int EB    = 2048;              // edges per binning block (391 blocks)

typedef short bf16x8 __attribute__((ext_vector_type(8)));
typedef float f32x4 __attribute__((ext_vector_type(4)));

__device__ __forceinline__ ushort f2bf(float f) {
  unsigned u = __float_as_uint(f);
  u = (u + 0x7FFFu + ((u >> 16) & 1u)) >> 16;
  return (ushort)u;
}
__device__ __forceinline__ float bflo(unsigned u) { return __uint_as_float(u << 16); }
__device__ __forceinline__ float bfhi(unsigned u) { return __uint_as_float(u & 0xFFFF0000u); }

// swizzled byte offset, 256B rows
__device__ __forceinline__ int swz(int row, int kbyte) {
  return row * 256 + (kbyte ^ ((row & 7) << 4));
}
// swizzled byte offset, 128B rows
__device__ __forceinline__ int swz128(int row, int kbyte) {
  return row * 128 + (kbyte ^ ((row & 7) << 4));
}

// ---------------- CSR build via bucket binning ----------------
__global__ __launch_bounds__(256) void k_initcur(int* __restrict__ cursor0) {
  int b = threadIdx.x;
  if (b < NBUCK) cursor0[b] = b * BCAP;
}

__global__ __launch_bounds__(256) void k_binA(const int* __restrict__ src, const int* __restrict__ dst,
                                              int* __restrict__ cursor0, int2* __restrict__ binned, int e) {
  __shared__ int cnt[NBUCK], base[NBUCK], cnt2[NBUCK];
  int t = threadIdx.x;
  for (int b = t; b < NBUCK; b += 256) { cnt[b] = 0; cnt2[b] = 0; }
  __syncthreads();
  int e0 = blockIdx.x * EB;
#pragma unroll
  for (int p = 0; p < EB / 256; ++p) {
    int i = e0 + p * 256 + t;
    if (i < e) atomicAdd(&cnt[dst[i] >> 9], 1);
  }
  __syncthreads();
  for (int b = t; b < NBUCK; b += 256)
    if (cnt[b] > 0) base[b] = atomicAdd(&cursor0[b], cnt[b]);
  __syncthreads();
#pragma unroll
  for (int p = 0; p < EB / 256; ++p) {
    int i = e0 + p * 256 + t;
    if (i < e) {
      int d = dst[i];
      int bk = d >> 9;
      int pos = base[bk] + atomicAdd(&cnt2[bk], 1);
      binned[pos] = make_int2(src[i], d);
    }
  }
}

__global__ __launch_bounds__(256) void k_degB(const int* __restrict__ cursor0,
                                              const int2* __restrict__ binned,
                                              int* __restrict__ deg, int n) {
  __shared__ int cnt[512];
  int b = blockIdx.x, t = threadIdx.x;
  cnt[t] = 0; cnt[t + 256] = 0;
  __syncthreads();
  int node0 = b << 9;
  int beg = b * BCAP;
  int cend = cursor0[b];
  for (int i = beg + t; i < cend; i += 256)
    atomicAdd(&cnt[binned[i].y - node0], 1);
  __syncthreads();
  if (node0 + t < n) deg[node0 + t] = cnt[t];
  if (node0 + t + 256 < n) deg[node0 + t + 256] = cnt[t + 256];
}

__global__ __launch_bounds__(1024) void k_scan1(const int* __restrict__ deg, int* __restrict__ rp,
                                                int* __restrict__ bsum, int n) {
  __shared__ int s[1024];
  int t = threadIdx.x;
  int i = blockIdx.x * 1024 + t;
  s[t] = (i < n) ? deg[i] : 0;
  __syncthreads();
  for (int off = 1; off < 1024; off <<= 1) {
    int x = (t >= off) ? s[t - off] : 0;
    __syncthreads();
    s[t] += x;
    __syncthreads();
  }
  if (i < n) rp[i + 1] = s[t];
  if (t == 1023) bsum[blockIdx.x] = s[1023];
}

__global__ __launch_bounds__(128) void k_scan2(int* __restrict__ bsum, int nb) {
  __shared__ int s[128];
  int t = threadIdx.x;
  s[t] = (t < nb) ? bsum[t] : 0;
  __syncthreads();
  for (int off = 1; off < 128; off <<= 1) {
    int x = (t >= off) ? s[t - off] : 0;
    __syncthreads();
    s[t] += x;
    __syncthreads();
  }
  if (t < nb) bsum[t] = s[t];
}

__global__ void k_scan3(int* __restrict__ rp, const int* __restrict__ bsum, int n) {
  int i = blockIdx.x * 256 + threadIdx.x;
  if (i == 0) rp[0] = 0;
  if (i < n) {
    int blk = i >> 10;
    rp[i + 1] = rp[i + 1] + ((blk > 0) ? bsum[blk - 1] : 0);
  }
}

__global__ __launch_bounds__(256) void k_scatC(const int* __restrict__ cursor0,
                                               const int2* __restrict__ binned,
                                               const int* __restrict__ rp,
                                               int* __restrict__ col, int n) {
  __shared__ int cur[512];
  __shared__ int lrp[512];
  int b = blockIdx.x, t = threadIdx.x;
  cur[t] = 0; cur[t + 256] = 0;
  int node0 = b << 9;
  lrp[t] = (node0 + t < n) ? rp[node0 + t] : 0;
  lrp[t + 256] = (node0 + t + 256 < n) ? rp[node0 + t + 256] : 0;
  __syncthreads();
  int beg = b * BCAP;
  int cend = cursor0[b];
  for (int i = beg + t; i < cend; i += 256) {
    int2 p = binned[i];
    int d = p.y - node0;
    int pos = lrp[d] + atomicAdd(&cur[d], 1);
    col[pos] = p.x;
  }
}

// ---------------- MFMA bf16 GEMM: out[n][128] = x[n][128] @ W[128][128]^T + b ----------------
template<bool INF32>
__global__ __launch_bounds__(256, 2) void k_mfma_gemm(const void* __restrict__ xin,
                                                      const float* __restrict__ W,
                                                      const float* __restrict__ bias,
                                                      ushort* __restrict__ outp, int n) {
  __shared__ __align__(16) char lds[65536];
  const int t = threadIdx.x;
  const int node0 = blockIdx.x * 128;

  if (INF32) {
#pragma unroll
    for (int p = 0; p < 16; ++p) {
      int F = p * 256 + t;
      int r = F >> 5, cchunk = F & 31;
      int node = node0 + r;
      float4 v = make_float4(0.f, 0.f, 0.f, 0.f);
      if (node < n) v = *(const float4*)((const float*)xin + (size_t)node * DD + cchunk * 4);
      ushort q[4] = {f2bf(v.x), f2bf(v.y), f2bf(v.z), f2bf(v.w)};
      *(unsigned long long*)(lds + swz(r, cchunk * 8)) = *(unsigned long long*)q;
    }
  } else {
#pragma unroll
    for (int p = 0; p < 8; ++p) {
      int F = p * 256 + t;
      int r = F >> 4, cchunk = F & 15;
      int node = node0 + r;
      uint4 v = make_uint4(0u, 0u, 0u, 0u);
      if (node < n) v = *(const uint4*)((const ushort*)xin + (size_t)node * DD + cchunk * 8);
      *(uint4*)(lds + swz(r, cchunk * 16)) = v;
    }
  }
  {
#pragma unroll
    for (int p = 0; p < 16; ++p) {
      int F = p * 256 + t;
      int r = F >> 5, cchunk = F & 31;
      float4 v = *(const float4*)(W + (size_t)r * DD + cchunk * 4);
      ushort q[4] = {f2bf(v.x), f2bf(v.y), f2bf(v.z), f2bf(v.w)};
      *(unsigned long long*)(lds + 32768 + swz(r, cchunk * 8)) = *(unsigned long long*)q;
    }
  }
  __syncthreads();

  const int lane = t & 63;
  const int l15 = lane & 15;
  const int lkb = (lane >> 4) * 16;
  const int wrow0 = (t >> 6) * 32;

  f32x4 acc[2][8];
#pragma unroll
  for (int j = 0; j < 8; ++j) {
    float bv = bias[j * 16 + l15];
    acc[0][j] = (f32x4){bv, bv, bv, bv};
    acc[1][j] = (f32x4){bv, bv, bv, bv};
  }

#pragma unroll
  for (int c = 0; c < 4; ++c) {
    bf16x8 a0 = *(const bf16x8*)(lds + swz(wrow0 + l15, c * 64 + lkb));
    bf16x8 a1 = *(const bf16x8*)(lds + swz(wrow0 + 16 + l15, c * 64 + lkb));
#pragma unroll
    for (int j = 0; j < 8; ++j) {
      bf16x8 b = *(const bf16x8*)(lds + 32768 + swz(j * 16 + l15, c * 64 + lkb));
      acc[0][j] = __builtin_amdgcn_mfma_f32_16x16x32_bf16(a0, b, acc[0][j], 0, 0, 0);
      acc[1][j] = __builtin_amdgcn_mfma_f32_16x16x32_bf16(a1, b, acc[1][j], 0, 0, 0);
    }
  }

  const int rbase = wrow0 + (lane >> 4) * 4;
#pragma unroll
  for (int i = 0; i < 2; ++i) {
#pragma unroll
    for (int r = 0; r < 4; ++r) {
      int node = node0 + rbase + i * 16 + r;
      if (node < n) {
#pragma unroll
        for (int j = 0; j < 8; ++j)
          outp[(size_t)node * DD + j * 16 + l15] = f2bf(acc[i][j][r]);
      }
    }
  }
}

// ---------------- GAT aggregate (bf16 h): per (dst,ch) softmax + weighted sum, relu ----------------
__global__ __launch_bounds__(256) void k_gat_agg(const ushort* __restrict__ h, const int* __restrict__ rp,
                                                 const int* __restrict__ col, const float* __restrict__ al,
                                                 const float* __restrict__ ar, ushort* __restrict__ out, int n) {
  int node = blockIdx.x * 4 + (threadIdx.x >> 6);
  int lane = threadIdx.x & 63;
  if (node >= n) return;
  const unsigned* hu = (const unsigned*)h;
  float al0 = al[2 * lane], al1 = al[2 * lane + 1];
  unsigned ud = hu[(unsigned)(node * 64 + lane)];
  float base0 = ar[2 * lane] * bflo(ud);
  float base1 = ar[2 * lane + 1] * bfhi(ud);
  int beg = __builtin_amdgcn_readfirstlane(rp[node]);
  int end = __builtin_amdgcn_readfirstlane(rp[node + 1]);
  float num0 = 0.f, num1 = 0.f, den0 = 0.f, den1 = 0.f;
#define ACCUM(U) { \
    float h0 = bflo(U), h1 = bfhi(U); \
    float w0 = __expf(fmaf(al0, h0, base0)); \
    float w1 = __expf(fmaf(al1, h1, base1)); \
    den0 += w0; den1 += w1; \
    num0 = fmaf(w0, h0, num0); num1 = fmaf(w1, h1, num1); }
  int j = beg;
  for (; j + 8 <= end; j += 8) {
    int s0 = __builtin_amdgcn_readfirstlane(col[j]);
    int s1 = __builtin_amdgcn_readfirstlane(col[j + 1]);
    int s2 = __builtin_amdgcn_readfirstlane(col[j + 2]);
    int s3 = __builtin_amdgcn_readfirstlane(col[j + 3]);
    int s4 = __builtin_amdgcn_readfirstlane(col[j + 4]);
    int s5 = __builtin_amdgcn_readfirstlane(col[j + 5]);
    int s6 = __builtin_amdgcn_readfirstlane(col[j + 6]);
    int s7 = __builtin_amdgcn_readfirstlane(col[j + 7]);
    unsigned u0 = hu[(unsigned)(s0 * 64 + lane)];
    unsigned u1 = hu[(unsigned)(s1 * 64 + lane)];
    unsigned u2 = hu[(unsigned)(s2 * 64 + lane)];
    unsigned u3 = hu[(unsigned)(s3 * 64 + lane)];
    unsigned u4 = hu[(unsigned)(s4 * 64 + lane)];
    unsigned u5 = hu[(unsigned)(s5 * 64 + lane)];
    unsigned u6 = hu[(unsigned)(s6 * 64 + lane)];
    unsigned u7 = hu[(unsigned)(s7 * 64 + lane)];
    ACCUM(u0); ACCUM(u1); ACCUM(u2); ACCUM(u3);
    ACCUM(u4); ACCUM(u5); ACCUM(u6); ACCUM(u7);
  }
  for (; j + 4 <= end; j += 4) {
    int s0 = __builtin_amdgcn_readfirstlane(col[j]);
    int s1 = __builtin_amdgcn_readfirstlane(col[j + 1]);
    int s2 = __builtin_amdgcn_readfirstlane(col[j + 2]);
    int s3 = __builtin_amdgcn_readfirstlane(col[j + 3]);
    unsigned u0 = hu[(unsigned)(s0 * 64 + lane)];
    unsigned u1 = hu[(unsigned)(s1 * 64 + lane)];
    unsigned u2 = hu[(unsigned)(s2 * 64 + lane)];
    unsigned u3 = hu[(unsigned)(s3 * 64 + lane)];
    ACCUM(u0); ACCUM(u1); ACCUM(u2); ACCUM(u3);
  }
  for (; j + 2 <= end; j += 2) {
    int s0 = __builtin_amdgcn_readfirstlane(col[j]);
    int s1 = __builtin_amdgcn_readfirstlane(col[j + 1]);
    unsigned u0 = hu[(unsigned)(s0 * 64 + lane)];
    unsigned u1 = hu[(unsigned)(s1 * 64 + lane)];
    ACCUM(u0); ACCUM(u1);
  }
  for (; j < end; ++j) {
    int s = __builtin_amdgcn_readfirstlane(col[j]);
    unsigned u = hu[(unsigned)(s * 64 + lane)];
    ACCUM(u);
  }
#undef ACCUM
  float o0 = fmaxf(num0 / (den0 + 1e-16f), 0.f);
  float o1 = fmaxf(num1 / (den1 + 1e-16f), 0.f);
  ((unsigned*)out)[(unsigned)(node * 64 + lane)] = (unsigned)f2bf(o0) | ((unsigned)f2bf(o1) << 16);
}

// ---------------- fused final: Wp1-MFMA -> LDS(bf16) -> Wp2-MFMA -> shfl log_softmax ----------------
__global__ __launch_bounds__(256, 2) void k_final_fused(const ushort* __restrict__ xin,
                                                        const float* __restrict__ W1,
                                                        const float* __restrict__ b1,
                                                        const float* __restrict__ Wp2,
                                                        const float* __restrict__ bp2,
                                                        float* __restrict__ out, int n) {
  __shared__ __align__(16) char lds[49152];
  const int t = threadIdx.x;
  const int node0 = blockIdx.x * 128;
  const int lane = t & 63;
  const int l15 = lane & 15;
  const int lg = lane >> 4;            // 0..3
  const int lkb = lg * 16;
  const int wrow0 = (t >> 6) * 32;

  // ---- phase A: stage x (bf16 128x128) + W1 (64x128 -> bf16) ----
#pragma unroll
  for (int p = 0; p < 8; ++p) {
    int F = p * 256 + t;
    int r = F >> 4, cchunk = F & 15;
    int node = node0 + r;
    uint4 v = make_uint4(0u, 0u, 0u, 0u);
    if (node < n) v = *(const uint4*)(xin + (size_t)node * DD + cchunk * 8);
    *(uint4*)(lds + swz(r, cchunk * 16)) = v;
  }
#pragma unroll
  for (int p = 0; p < 8; ++p) {
    int F = p * 256 + t;
    int r = F >> 5, cchunk = F & 31;
    float4 v = *(const float4*)(W1 + (size_t)r * DD + cchunk * 4);
    ushort q[4] = {f2bf(v.x), f2bf(v.y), f2bf(v.z), f2bf(v.w)};
    *(unsigned long long*)(lds + 32768 + swz(r, cchunk * 8)) = *(unsigned long long*)q;
  }
  __syncthreads();

  // ---- MFMA-1: h1[128 nodes][64] = x @ W1^T + b1 ----
  f32x4 acc[2][4];
#pragma unroll
  for (int j = 0; j < 4; ++j) {
    float bv = b1[j * 16 + l15];
    acc[0][j] = (f32x4){bv, bv, bv, bv};
    acc[1][j] = (f32x4){bv, bv, bv, bv};
  }
#pragma unroll
  for (int c = 0; c < 4; ++c) {
    bf16x8 a0 = *(const bf16x8*)(lds + swz(wrow0 + l15, c * 64 + lkb));
    bf16x8 a1 = *(const bf16x8*)(lds + swz(wrow0 + 16 + l15, c * 64 + lkb));
#pragma unroll
    for (int j = 0; j < 4; ++j) {
      bf16x8 b = *(const bf16x8*)(lds + 32768 + swz(j * 16 + l15, c * 64 + lkb));
      acc[0][j] = __builtin_amdgcn_mfma_f32_16x16x32_bf16(a0, b, acc[0][j], 0, 0, 0);
      acc[1][j] = __builtin_amdgcn_mfma_f32_16x16x32_bf16(a1, b, acc[1][j], 0, 0, 0);
    }
  }
  __syncthreads();   // done reading x/W1; reuse LDS

  // ---- phase B: h1 -> LDS bf16 [128 nodes][64ch] (128B swizzled rows); Wp2 -> [48][64] bf16 ----
  char* h1L = lds;                   // 16 KB
  char* wpL = lds + 16384;           // 6 KB
  const int rbase = wrow0 + lg * 4;
#pragma unroll
  for (int i = 0; i < 2; ++i)
#pragma unroll
    for (int r = 0; r < 4; ++r) {
      int row = rbase + i * 16 + r;
#pragma unroll
      for (int j = 0; j < 4; ++j)
        *(ushort*)(h1L + swz128(row, (j * 16 + l15) * 2)) = f2bf(acc[i][j][r]);
    }
  // stage Wp2: 48 rows x 64 ch (rows 40..47 zero)
#pragma unroll
  for (int p = 0; p < 3; ++p) {
    int flat = p * 1024 + t * 4;        // element index, 4 per thread
    int row = flat >> 6, ch0 = flat & 63;
    float4 v = make_float4(0.f, 0.f, 0.f, 0.f);
    if (row < OUTC) v = *(const float4*)(Wp2 + row * 64 + ch0);
    ushort q[4] = {f2bf(v.x), f2bf(v.y), f2bf(v.z), f2bf(v.w)};
    *(unsigned long long*)(wpL + swz128(row, ch0 * 2)) = *(unsigned long long*)q;
  }
  __syncthreads();

  // ---- MFMA-2: logits[128 nodes][48] = h1 @ Wp2^T (+bp2 via init; pad classes -> -1e30) ----
  f32x4 acc2[2][3];
#pragma unroll
  for (int j = 0; j < 3; ++j) {
    int cls = j * 16 + l15;
    float bv = (cls < OUTC) ? bp2[cls] : -1e30f;
    acc2[0][j] = (f32x4){bv, bv, bv, bv};
    acc2[1][j] = (f32x4){bv, bv, bv, bv};
  }
#pragma unroll
  for (int c2 = 0; c2 < 2; ++c2) {
    bf16x8 a0 = *(const bf16x8*)(h1L + swz128(wrow0 + l15, c2 * 64 + lkb));
    bf16x8 a1 = *(const bf16x8*)(h1L + swz128(wrow0 + 16 + l15, c2 * 64 + lkb));
#pragma unroll
    for (int j = 0; j < 3; ++j) {
      bf16x8 b = *(const bf16x8*)(wpL + swz128(j * 16 + l15, c2 * 64 + lkb));
      acc2[0][j] = __builtin_amdgcn_mfma_f32_16x16x32_bf16(a0, b, acc2[0][j], 0, 0, 0);
      acc2[1][j] = __builtin_amdgcn_mfma_f32_16x16x32_bf16(a1, b, acc2[1][j], 0, 0, 0);
    }
  }

  // ---- log_softmax per node row (reduce across 16 lanes of the group) + store ----
#pragma unroll
  for (int i = 0; i < 2; ++i) {
#pragma unroll
    for (int r = 0; r < 4; ++r) {
      float u0 = acc2[i][0][r], u1 = acc2[i][1][r], u2 = acc2[i][2][r];
      float m = fmaxf(fmaxf(u0, u1), u2);
#pragma unroll
      for (int d = 1; d < 16; d <<= 1) m = fmaxf(m, __shfl_xor(m, d, 64));
      float s = __expf(u0 - m) + __expf(u1 - m) + __expf(u2 - m);
#pragma unroll
      for (int d = 1; d < 16; d <<= 1) s += __shfl_xor(s, d, 64);
      float ls = __logf(s) + m;
      int node = node0 + rbase + i * 16 + r;
      if (node < n) {
        float* op = out + (size_t)node * OUTC;
        op[l15] = u0 - ls;
        op[16 + l15] = u1 - ls;
        if (l15 < 8) op[32 + l15] = u2 - ls;
      }
    }
  }
}

extern "C" void kernel_launch(void* const* d_in, const int* in_sizes, int n_in,
                              void* d_out, int out_size, void* d_ws, size_t ws_size,
                              hipStream_t stream) {
  const float* x   = (const float*)d_in[0];
  const int*   ei  = (const int*)d_in[1];
  const float* W[3]  = {(const float*)d_in[2],  (const float*)d_in[6],  (const float*)d_in[10]};
  const float* B[3]  = {(const float*)d_in[3],  (const float*)d_in[7],  (const float*)d_in[11]};
  const float* AL[3] = {(const float*)d_in[4],  (const float*)d_in[8],  (const float*)d_in[12]};
  const float* AR[3] = {(const float*)d_in[5],  (const float*)d_in[9],  (const float*)d_in[13]};
  const float* Wp1 = (const float*)d_in[14];
  const float* bp1 = (const float*)d_in[15];
  const float* Wp2 = (const float*)d_in[16];
  const float* bp2 = (const float*)d_in[17];
  float* outp = (float*)d_out;

  const int n = NN, e = EE;
  const int* srcp = ei;
  const int* dstp = ei + e;

  char* ws = (char*)d_ws;
  size_t off = 0;
  auto alloc = [&](size_t bytes) { void* p = ws + off; off = (off + bytes + 255) & ~(size_t)255; return p; };
  ushort* bhA = (ushort*)alloc((size_t)n * DD * 2);   // bf16 h (pre-agg)
  ushort* bhB = (ushort*)alloc((size_t)n * DD * 2);   // bf16 h (post-agg)
  int*   deg   = (int*)alloc((size_t)n * 4);
  int*   rp    = (int*)alloc((size_t)(n + 1) * 4);
  int*   bsum  = (int*)alloc(1024 * 4);
  int*   col   = (int*)alloc((size_t)e * 4);
  int*   cursor0 = (int*)alloc((size_t)NBUCK * 4);
  int2*  binned  = (int2*)alloc((size_t)NBUCK * BCAP * 8);
  (void)ws_size;

  // CSR build (by dst) via bucket binning — no random 4B scatters to HBM
  k_initcur<<<1, 256, 0, stream>>>(cursor0);
  k_binA<<<(e + EB - 1) / EB, 256, 0, stream>>>(srcp, dstp, cursor0, binned, e);
  k_degB<<<NBUCK, 256, 0, stream>>>(cursor0, binned, deg, n);
  int nb = (n + 1023) / 1024;
  k_scan1<<<nb, 1024, 0, stream>>>(deg, rp, bsum, n);
  k_scan2<<<1, 128, 0, stream>>>(bsum, nb);
  k_scan3<<<(n + 255) / 256, 256, 0, stream>>>(rp, bsum, n);
  k_scatC<<<NBUCK, 256, 0, stream>>>(cursor0, binned, rp, col, n);

  const int gblocks = (n + 127) / 128;
  const int ablocks = (n + 3) / 4;
  // layer 0: f32 x -> bf16 h
  k_mfma_gemm<true><<<gblocks, 256, 0, stream>>>(x, W[0], B[0], bhA, n);
  k_gat_agg<<<ablocks, 256, 0, stream>>>(bhA, rp, col, AL[0], AR[0], bhB, n);
  // layers 1,2: bf16 -> bf16
  for (int l = 1; l < 3; ++l) {
    k_mfma_gemm<false><<<gblocks, 256, 0, stream>>>(bhB, W[l], B[l], bhA, n);
    k_gat_agg<<<ablocks, 256, 0, stream>>>(bhA, rp, col, AL[l], AR[l], bhB, n);
  }
  // fused final MLP + log_softmax (MFMA both stages)
  k_final_fused<<<gblocks, 256, 0, stream>>>(bhB, Wp1, bp1, Wp2, bp2, outp, n);
}